// Round 3
// baseline (7879.362 us; speedup 1.0000x reference)
//
#include <hip/hip_runtime.h>
#include <math.h>

#define BB 128
#define NN 100
#define LL 30
#define CC 512
#define DFEAT 2112
#define TT 4
#define ROWS (BB * NN)          // 12800
#define INV_SQRT_C_F 0.04419417382415922f
#define QH 50                    // q-rows per attention block (2 halves)
#define LDS_STRIDE 132           // padded row stride for GEMM LDS tiles

// ---------------------------------------------------------------------------
// inv_norm[r] = 1 / max(||images[r,:]||, 1e-12)
// ---------------------------------------------------------------------------
__global__ __launch_bounds__(256) void rownorm_kernel(const float* __restrict__ img,
                                                      float* __restrict__ inv_norm) {
    int r = blockIdx.x;
    const float* p = img + (size_t)r * DFEAT;
    float s = 0.f;
    for (int i = threadIdx.x; i < DFEAT; i += 256) { float v = p[i]; s += v * v; }
    __shared__ float red[4];
    int lane = threadIdx.x & 63, wid = threadIdx.x >> 6;
#pragma unroll
    for (int off = 32; off > 0; off >>= 1) s += __shfl_down(s, off);
    if (lane == 0) red[wid] = s;
    __syncthreads();
    if (threadIdx.x == 0) {
        float tot = red[0] + red[1] + red[2] + red[3];
        inv_norm[r] = 1.f / fmaxf(sqrtf(tot), 1e-12f);
    }
}

// ---------------------------------------------------------------------------
// broadcast initMem[512] over [ROWS,512]
// ---------------------------------------------------------------------------
__global__ void bcast_kernel(const float* __restrict__ m, float* __restrict__ x, int total) {
    int i = blockIdx.x * blockDim.x + threadIdx.x;
    if (i < total) x[i] = m[i & (CC - 1)];
}

// ---------------------------------------------------------------------------
// GEMM: C[m,n] (op)= sum_k A[m,k] * W[n,k]   (W row-major [512, ldw-chunks])
// C row stride fixed at CC=512. Tiles: 128x128x16, 256 thr, 8x8 micro-tile.
// MODE 0: C = acc + bias[n]
// MODE 1: C = C + acc
// MODE 2: C = C * (acc + bias[n])                       (proj_loc * proj_ctx)
// MODE 3: C = (C + acc) * rowscale[(m/100)*512 + n]     (keys/vals cmd gate)
// MODE 4: C = elu(acc + bias[n])
// arsc (optional): per-row scale applied to A during load (image normalize)
// ---------------------------------------------------------------------------
template <int MODE>
__global__ __launch_bounds__(256) void gemm_kernel(
    const float* __restrict__ A, int lda,
    const float* __restrict__ W, int ldw,
    const float* __restrict__ bias,
    float* __restrict__ C,
    int M, int K,
    const float* __restrict__ arsc,
    const float* __restrict__ rowscale) {
    __shared__ float As[16 * LDS_STRIDE];
    __shared__ float Bs[16 * LDS_STRIDE];
    const int t = threadIdx.x;
    const int m0 = blockIdx.x * 128;
    const int n0 = blockIdx.y * 128;
    const int tr = t >> 4, tc = t & 15;
    float acc[8][8];
#pragma unroll
    for (int i = 0; i < 8; ++i)
#pragma unroll
        for (int j = 0; j < 8; ++j) acc[i][j] = 0.f;

    for (int k0 = 0; k0 < K; k0 += 16) {
#pragma unroll
        for (int i = 0; i < 2; ++i) {
            int lin = t + i * 256;
            int row = lin >> 2, seg = lin & 3;
            float4 v = *(const float4*)(A + (size_t)(m0 + row) * lda + k0 + seg * 4);
            if (arsc) { float s = arsc[m0 + row]; v.x *= s; v.y *= s; v.z *= s; v.w *= s; }
            As[(seg * 4 + 0) * LDS_STRIDE + row] = v.x;
            As[(seg * 4 + 1) * LDS_STRIDE + row] = v.y;
            As[(seg * 4 + 2) * LDS_STRIDE + row] = v.z;
            As[(seg * 4 + 3) * LDS_STRIDE + row] = v.w;
        }
#pragma unroll
        for (int i = 0; i < 2; ++i) {
            int lin = t + i * 256;
            int row = lin >> 2, seg = lin & 3;
            float4 v = *(const float4*)(W + (size_t)(n0 + row) * ldw + k0 + seg * 4);
            Bs[(seg * 4 + 0) * LDS_STRIDE + row] = v.x;
            Bs[(seg * 4 + 1) * LDS_STRIDE + row] = v.y;
            Bs[(seg * 4 + 2) * LDS_STRIDE + row] = v.z;
            Bs[(seg * 4 + 3) * LDS_STRIDE + row] = v.w;
        }
        __syncthreads();
#pragma unroll
        for (int kk = 0; kk < 16; ++kk) {
            float af[8], bf[8];
            *(float4*)&af[0] = *(const float4*)&As[kk * LDS_STRIDE + tr * 8];
            *(float4*)&af[4] = *(const float4*)&As[kk * LDS_STRIDE + tr * 8 + 4];
            *(float4*)&bf[0] = *(const float4*)&Bs[kk * LDS_STRIDE + tc * 8];
            *(float4*)&bf[4] = *(const float4*)&Bs[kk * LDS_STRIDE + tc * 8 + 4];
#pragma unroll
            for (int i = 0; i < 8; ++i)
#pragma unroll
                for (int j = 0; j < 8; ++j) acc[i][j] = fmaf(af[i], bf[j], acc[i][j]);
        }
        __syncthreads();
    }
#pragma unroll
    for (int i = 0; i < 8; ++i) {
        int r = m0 + tr * 8 + i;
        float* crow = C + (size_t)r * CC + n0 + tc * 8;
#pragma unroll
        for (int j = 0; j < 8; ++j) {
            float v = acc[i][j];
            int n = n0 + tc * 8 + j;
            if (MODE == 0) {
                v += bias[n];
            } else if (MODE == 1) {
                v += crow[j];
            } else if (MODE == 2) {
                v = crow[j] * (v + bias[n]);
            } else if (MODE == 3) {
                v = (crow[j] + v) * rowscale[(size_t)(r / NN) * CC + n];
            } else if (MODE == 4) {
                v += bias[n];
                v = v > 0.f ? v : expm1f(v);
            }
            crow[j] = v;
        }
    }
}

// ---------------------------------------------------------------------------
// Per-batch command extraction:
//   raw[l]  = sum_c qcmd[b,c]*wl[c]*lstm[b,l,c] + bl
//   att     = softmax(raw masked by l < qlen[b])
//   cmd[b,c]= sum_l att[l]*lstm[b,l,c]
// ---------------------------------------------------------------------------
__global__ __launch_bounds__(256) void cmd_kernel(
    const float* __restrict__ qcmd, const float* __restrict__ lstm,
    const float* __restrict__ wlogit, const float* __restrict__ blogit,
    const int* __restrict__ qlen, float* __restrict__ cmd) {
    const int b = blockIdx.x;
    const int t = threadIdx.x;
    __shared__ float qw[CC];
    __shared__ float att[LL];
    for (int c = t; c < CC; c += 256) qw[c] = qcmd[b * CC + c] * wlogit[c];
    __syncthreads();
    const int wid = t >> 6, lane = t & 63;
    for (int l = wid; l < LL; l += 4) {
        const float* lp = lstm + ((size_t)b * LL + l) * CC;
        float s = 0.f;
        for (int c = lane; c < CC; c += 64) s = fmaf(qw[c], lp[c], s);
#pragma unroll
        for (int off = 32; off > 0; off >>= 1) s += __shfl_down(s, off);
        if (lane == 0) att[l] = s + blogit[0];
    }
    __syncthreads();
    if (t == 0) {
        int Lq = qlen[b];
        float mx = -1e30f;
        for (int l = 0; l < LL; ++l) {
            if (l >= Lq) att[l] = -1e30f;
            mx = fmaxf(mx, att[l]);
        }
        float sum = 0.f;
        for (int l = 0; l < LL; ++l) { float e = expf(att[l] - mx); att[l] = e; sum += e; }
        float inv = 1.f / sum;
        for (int l = 0; l < LL; ++l) att[l] *= inv;
    }
    __syncthreads();
    for (int c = t; c < CC; c += 256) {
        float s = 0.f;
        for (int l = 0; l < LL; ++l) s = fmaf(att[l], lstm[((size_t)b * LL + l) * CC + c], s);
        cmd[b * CC + c] = s;
    }
}

// ---------------------------------------------------------------------------
// Fused attention: per (b, q-half): S = Q Kt / sqrt(C); masked softmax over k;
// msg = P V.  grid (128, 2), block 256.
// ---------------------------------------------------------------------------
__global__ __launch_bounds__(256) void attn_kernel(
    const float* __restrict__ Qm, const float* __restrict__ Km,
    const float* __restrict__ Vm, const int* __restrict__ entnum,
    float* __restrict__ msg) {
    __shared__ float S[QH * NN];      // 5000 floats; first 50*65 alias the Q chunk buf
    __shared__ float Bbuf[NN * 65];   // K / V chunk, padded
    float* Abuf = S;                  // [QH][65] during phase A only
    const int b = blockIdx.x;
    const int qbase = blockIdx.y * QH;
    const int t = threadIdx.x;
    const int tq = t >> 4, tk = t & 15;
    const float* Qp = Qm + ((size_t)b * NN + qbase) * CC;
    const float* Kp = Km + (size_t)b * NN * CC;
    const float* Vp = Vm + (size_t)b * NN * CC;

    float acc[4][7];
#pragma unroll
    for (int i = 0; i < 4; ++i)
#pragma unroll
        for (int j = 0; j < 7; ++j) acc[i][j] = 0.f;

    // ---- phase A: scores ----
    for (int c0 = 0; c0 < CC; c0 += 64) {
        for (int lin = t; lin < QH * 64; lin += 256) {
            int row = lin >> 6, col = lin & 63;
            Abuf[row * 65 + col] = Qp[(size_t)row * CC + c0 + col];
        }
        for (int lin = t; lin < NN * 64; lin += 256) {
            int row = lin >> 6, col = lin & 63;
            Bbuf[row * 65 + col] = Kp[(size_t)row * CC + c0 + col];
        }
        __syncthreads();
#pragma unroll 8
        for (int kk = 0; kk < 64; ++kk) {
            float a[4], bb[7];
#pragma unroll
            for (int i = 0; i < 4; ++i) { int q = tq + 16 * i; a[i] = (q < QH) ? Abuf[q * 65 + kk] : 0.f; }
#pragma unroll
            for (int j = 0; j < 7; ++j) { int k = tk + 16 * j; bb[j] = (k < NN) ? Bbuf[k * 65 + kk] : 0.f; }
#pragma unroll
            for (int i = 0; i < 4; ++i)
#pragma unroll
                for (int j = 0; j < 7; ++j) acc[i][j] = fmaf(a[i], bb[j], acc[i][j]);
        }
        __syncthreads();
    }
#pragma unroll
    for (int i = 0; i < 4; ++i) {
        int q = tq + 16 * i;
        if (q < QH) {
#pragma unroll
            for (int j = 0; j < 7; ++j) {
                int k = tk + 16 * j;
                if (k < NN) S[q * NN + k] = acc[i][j] * INV_SQRT_C_F;
            }
        }
    }
    __syncthreads();

    // ---- phase B: masked softmax over k ----
    const int en = entnum[b];
    const int wid = t >> 6, lane = t & 63;
    for (int q = wid; q < QH; q += 4) {
        float v0 = (lane < en) ? S[q * NN + lane] : -1e30f;
        int k1 = lane + 64;
        float v1 = (k1 < NN && k1 < en) ? S[q * NN + k1] : -1e30f;
        float mx = fmaxf(v0, v1);
#pragma unroll
        for (int o = 32; o > 0; o >>= 1) mx = fmaxf(mx, __shfl_xor(mx, o));
        float e0 = expf(v0 - mx), e1 = expf(v1 - mx);
        float ss = e0 + e1;
#pragma unroll
        for (int o = 32; o > 0; o >>= 1) ss += __shfl_xor(ss, o);
        float inv = 1.f / ss;
        if (lane < NN) S[q * NN + lane] = e0 * inv;
        if (k1 < NN) S[q * NN + k1] = e1 * inv;
    }
    __syncthreads();

    // ---- phase C: msg = P V ----
    const int tcc = t & 63, tqq = t >> 6;
    for (int c0 = 0; c0 < CC; c0 += 64) {
        for (int lin = t; lin < NN * 64; lin += 256) {
            int row = lin >> 6, col = lin & 63;
            Bbuf[row * 65 + col] = Vp[(size_t)row * CC + c0 + col];
        }
        __syncthreads();
        for (int q = tqq; q < QH; q += 4) {
            float s = 0.f;
#pragma unroll 4
            for (int k = 0; k < NN; ++k) s = fmaf(S[q * NN + k], Bbuf[k * 65 + tcc], s);
            msg[((size_t)b * NN + qbase + q) * CC + c0 + tcc] = s;
        }
        __syncthreads();
    }
}

// ---------------------------------------------------------------------------
extern "C" void kernel_launch(void* const* d_in, const int* in_sizes, int n_in,
                              void* d_out, int out_size, void* d_ws, size_t ws_size,
                              hipStream_t stream) {
    const float* images   = (const float*)d_in[0];
    const float* q_enc    = (const float*)d_in[1];
    const float* lstm     = (const float*)d_in[2];
    const float* W_initKB = (const float*)d_in[3];
    const float* b_initKB = (const float*)d_in[4];
    const float* initMem  = (const float*)d_in[5];
    const float* W_qIn    = (const float*)d_in[6];
    const float* b_qIn    = (const float*)d_in[7];
    const float* W_qIn2   = (const float*)d_in[8];
    const float* b_qIn2   = (const float*)d_in[9];
    const float* W_logit  = (const float*)d_in[10];
    const float* b_logit  = (const float*)d_in[11];
    const float* W_ploc   = (const float*)d_in[12];
    const float* b_ploc   = (const float*)d_in[13];
    const float* W_pctx   = (const float*)d_in[14];
    const float* b_pctx   = (const float*)d_in[15];
    const float* W_q      = (const float*)d_in[16];
    const float* b_q      = (const float*)d_in[17];
    const float* W_k      = (const float*)d_in[18];
    const float* b_k      = (const float*)d_in[19];
    const float* W_v      = (const float*)d_in[20];
    const float* b_v      = (const float*)d_in[21];
    const float* W_pk     = (const float*)d_in[22];
    const float* b_pk     = (const float*)d_in[23];
    const float* W_pv     = (const float*)d_in[24];
    const float* b_pv     = (const float*)d_in[25];
    const float* W_mem    = (const float*)d_in[26];
    const float* b_mem    = (const float*)d_in[27];
    const float* W_comb   = (const float*)d_in[28];
    const float* b_comb   = (const float*)d_in[29];
    const int* q_length   = (const int*)d_in[30];
    const int* entity_num = (const int*)d_in[31];

    float* ws = (float*)d_ws;
    size_t off = 0;
    auto alloc = [&](size_t n) { float* p = ws + off; off += n; return p; };
    const size_t RC = (size_t)ROWS * CC;
    float* x_loc = alloc(RC);
    float* X0    = alloc(RC);
    float* X1    = alloc(RC);
    float* prod  = alloc(RC);           // proj_loc*proj_ctx; reused for message
    float* Qb    = alloc(RC);
    float* Kbuf  = alloc(RC);
    float* Vbuf  = (float*)d_out;       // V lives in d_out until the final GEMMs
    float* qcb   = alloc((size_t)BB * CC);
    float* qcmd  = alloc((size_t)BB * CC);
    float* cmd   = alloc((size_t)BB * CC);
    float* pk    = alloc((size_t)BB * CC);
    float* pv    = alloc((size_t)BB * CC);
    float* invn  = alloc(ROWS);
    (void)ws_size; (void)in_sizes; (void)n_in; (void)out_size;

    auto gemm = [&](int mode, const float* A, int lda, const float* W, int ldw,
                    const float* bias, float* C, int M, int K,
                    const float* arsc, const float* rs) {
        dim3 grid(M / 128, CC / 128);
        dim3 block(256);
        switch (mode) {
            case 0: gemm_kernel<0><<<grid, block, 0, stream>>>(A, lda, W, ldw, bias, C, M, K, arsc, rs); break;
            case 1: gemm_kernel<1><<<grid, block, 0, stream>>>(A, lda, W, ldw, bias, C, M, K, arsc, rs); break;
            case 2: gemm_kernel<2><<<grid, block, 0, stream>>>(A, lda, W, ldw, bias, C, M, K, arsc, rs); break;
            case 3: gemm_kernel<3><<<grid, block, 0, stream>>>(A, lda, W, ldw, bias, C, M, K, arsc, rs); break;
            case 4: gemm_kernel<4><<<grid, block, 0, stream>>>(A, lda, W, ldw, bias, C, M, K, arsc, rs); break;
        }
    };

    // stem
    rownorm_kernel<<<dim3(ROWS), dim3(256), 0, stream>>>(images, invn);
    gemm(0, images, DFEAT, W_initKB, DFEAT, b_initKB, x_loc, ROWS, DFEAT, invn, nullptr);
    bcast_kernel<<<dim3((ROWS * CC + 255) / 256), dim3(256), 0, stream>>>(initMem, X0, ROWS * CC);
    gemm(4, q_enc, CC, W_qIn, CC, b_qIn, qcb, BB, CC, nullptr, nullptr);

    float* xc = X0;
    float* xn = X1;
    for (int t = 0; t < TT; ++t) {
        // textual command
        gemm(0, qcb, CC, W_qIn2 + (size_t)t * CC * CC, CC, b_qIn2 + (size_t)t * CC, qcmd, BB, CC, nullptr, nullptr);
        cmd_kernel<<<dim3(BB), dim3(256), 0, stream>>>(qcmd, lstm, W_logit, b_logit, q_length, cmd);
        gemm(0, cmd, CC, W_pk, CC, b_pk, pk, BB, CC, nullptr, nullptr);
        gemm(0, cmd, CC, W_pv, CC, b_pv, pv, BB, CC, nullptr, nullptr);
        // proj_loc * proj_ctx
        gemm(0, x_loc, CC, W_ploc, CC, b_ploc, prod, ROWS, CC, nullptr, nullptr);
        gemm(2, xc,    CC, W_pctx, CC, b_pctx, prod, ROWS, CC, nullptr, nullptr);
        // queries / keys / vals as 3 accumulating chunk-GEMMs over x_joint = [x_loc|xc|prod]
        gemm(0, x_loc, CC, W_q,          3 * CC, b_q,     Qb,   ROWS, CC, nullptr, nullptr);
        gemm(1, xc,    CC, W_q + CC,     3 * CC, nullptr, Qb,   ROWS, CC, nullptr, nullptr);
        gemm(1, prod,  CC, W_q + 2 * CC, 3 * CC, nullptr, Qb,   ROWS, CC, nullptr, nullptr);
        gemm(0, x_loc, CC, W_k,          3 * CC, b_k,     Kbuf, ROWS, CC, nullptr, nullptr);
        gemm(1, xc,    CC, W_k + CC,     3 * CC, nullptr, Kbuf, ROWS, CC, nullptr, nullptr);
        gemm(3, prod,  CC, W_k + 2 * CC, 3 * CC, nullptr, Kbuf, ROWS, CC, nullptr, pk);
        gemm(0, x_loc, CC, W_v,          3 * CC, b_v,     Vbuf, ROWS, CC, nullptr, nullptr);
        gemm(1, xc,    CC, W_v + CC,     3 * CC, nullptr, Vbuf, ROWS, CC, nullptr, nullptr);
        gemm(3, prod,  CC, W_v + 2 * CC, 3 * CC, nullptr, Vbuf, ROWS, CC, nullptr, pv);
        // attention (message written into prod, which is free now)
        attn_kernel<<<dim3(BB, 2), dim3(256), 0, stream>>>(Qb, Kbuf, Vbuf, entity_num, prod);
        // memory update: xn = [xc | message] @ W_mem.T + b_mem
        gemm(0, xc,   CC, W_mem,      2 * CC, b_mem,   xn, ROWS, CC, nullptr, nullptr);
        gemm(1, prod, CC, W_mem + CC, 2 * CC, nullptr, xn, ROWS, CC, nullptr, nullptr);
        float* tmp = xc; xc = xn; xn = tmp;
    }
    // output = [x_loc | x_ctx] @ W_comb.T + b_comb
    float* out = (float*)d_out;
    gemm(0, x_loc, CC, W_comb,      2 * CC, b_comb,  out, ROWS, CC, nullptr, nullptr);
    gemm(1, xc,    CC, W_comb + CC, 2 * CC, nullptr, out, ROWS, CC, nullptr, nullptr);
}

// Round 4
// 2544.535 us; speedup vs baseline: 3.0966x; 3.0966x over previous
//
#include <hip/hip_runtime.h>
#include <math.h>

#define BB 128
#define NN 100
#define LL 30
#define CC 512
#define DFEAT 2112
#define TT 4
#define ROWS (BB * NN)          // 12800
#define XJLD 1536               // x_joint row stride (bf16): [x_loc | x_ctx | prod]
#define INV_SQRT_C_F 0.04419417382415922f
#define QH 50                    // q-rows per attention block (2 halves)

typedef __attribute__((ext_vector_type(8))) short short8;
typedef __attribute__((ext_vector_type(4))) float f32x4;

__device__ inline unsigned short f2bf(float f) {
    unsigned u = __float_as_uint(f);
    u += 0x7fff + ((u >> 16) & 1);          // round-to-nearest-even
    return (unsigned short)(u >> 16);
}
__device__ inline float b2f(unsigned short h) { return __uint_as_float((unsigned)h << 16); }

__device__ inline void async_ld16(const unsigned short* g, unsigned short* l) {
    __builtin_amdgcn_global_load_lds((const __attribute__((address_space(1))) void*)g,
                                     (__attribute__((address_space(3))) void*)l, 16, 0, 0);
}

// ---------------------------------------------------------------------------
// inv_norm[r] = 1 / max(||images[r,:]||, 1e-12)
// ---------------------------------------------------------------------------
__global__ __launch_bounds__(256) void rownorm_kernel(const float* __restrict__ img,
                                                      float* __restrict__ inv_norm) {
    int r = blockIdx.x;
    const float* p = img + (size_t)r * DFEAT;
    float s = 0.f;
    for (int i = threadIdx.x; i < DFEAT; i += 256) { float v = p[i]; s += v * v; }
    __shared__ float red[4];
    int lane = threadIdx.x & 63, wid = threadIdx.x >> 6;
#pragma unroll
    for (int off = 32; off > 0; off >>= 1) s += __shfl_down(s, off);
    if (lane == 0) red[wid] = s;
    __syncthreads();
    if (threadIdx.x == 0) {
        float tot = red[0] + red[1] + red[2] + red[3];
        inv_norm[r] = 1.f / fmaxf(sqrtf(tot), 1e-12f);
    }
}

// ---------------------------------------------------------------------------
// fp32 -> bf16 weight conversion (vectorized, n4 = n/4)
// ---------------------------------------------------------------------------
__global__ __launch_bounds__(256) void cvt_kernel(const float* __restrict__ s,
                                                  unsigned short* __restrict__ d, int n4) {
    int i = blockIdx.x * blockDim.x + threadIdx.x;
    if (i < n4) {
        float4 v = ((const float4*)s)[i];
        ushort4 o;
        o.x = f2bf(v.x); o.y = f2bf(v.y); o.z = f2bf(v.z); o.w = f2bf(v.w);
        ((ushort4*)d)[i] = o;
    }
}

// ---------------------------------------------------------------------------
// broadcast initMem[512] (fp32) into XJ0 x_ctx column (bf16, stride XJLD)
// ---------------------------------------------------------------------------
__global__ void bcast_kernel(const float* __restrict__ m, unsigned short* __restrict__ x) {
    int i = blockIdx.x * blockDim.x + threadIdx.x;
    if (i < ROWS * CC) {
        int r = i >> 9, c = i & (CC - 1);
        x[(size_t)r * XJLD + CC + c] = f2bf(m[c]);
    }
}

// ---------------------------------------------------------------------------
// MFMA GEMM: C[m,n] = epi( sum_k A[m,k] * W[n,k] )  -- W row-major [512][ldw] bf16
// tile 128x128, BK=32, 4 waves each owning a 64x64 quadrant (4x4 frags of
// 16x16x32 bf16 MFMA). N fixed 512 (grid.y = 4), M = grid.x*128.
// MODE 0: v = acc + bias[n]
// MODE 2: v = (acc + bias[n]) * C_prev   (proj_loc * proj_ctx, in-place on C)
// MODE 3: v = (acc + bias[n]) * rowscale[(r/100)*512 + n]
// AF32: A is fp32 (stem; reg-staged with optional row scale arsc), else bf16
//       staged via global_load_lds width-16.
// OUTF32: write fp32 (d_out), else bf16.  DUAL: also write C2 (stem).
// ---------------------------------------------------------------------------
template <int MODE, bool AF32, bool OUTF32, bool DUAL>
__global__ __launch_bounds__(256) void gemm_mfma(
    const void* __restrict__ A_, int lda,
    const unsigned short* __restrict__ W, int ldw,
    const float* __restrict__ bias,
    void* __restrict__ C_, int ldc,
    void* __restrict__ C2_,
    int K,
    const float* __restrict__ arsc,
    const float* __restrict__ rowscale) {
    __shared__ unsigned short As[128 * 32];
    __shared__ unsigned short Bs[128 * 32];
    const int t = threadIdx.x;
    const int l = t & 63;
    const int wv = t >> 6;
    const int wr = wv >> 1, wc = wv & 1;
    const int lg = l >> 4, lm = l & 15;
    const int m0 = blockIdx.x * 128, n0 = blockIdx.y * 128;

    f32x4 acc[4][4];
#pragma unroll
    for (int mi = 0; mi < 4; ++mi)
#pragma unroll
        for (int ni = 0; ni < 4; ++ni) acc[mi][ni] = {0.f, 0.f, 0.f, 0.f};

    for (int k0 = 0; k0 < K; k0 += 32) {
        if (AF32) {
            // reg-stage fp32 A -> bf16 LDS (row-major [128][32])
            const float* Af = (const float*)A_;
            int row = t >> 1, half = t & 1;
            const float* s = Af + (size_t)(m0 + row) * lda + k0 + half * 16;
            float sc = arsc ? arsc[m0 + row] : 1.f;
            float4 v0 = *(const float4*)s, v1 = *(const float4*)(s + 4);
            float4 v2 = *(const float4*)(s + 8), v3 = *(const float4*)(s + 12);
            short8 h0, h1;
            h0[0] = (short)f2bf(v0.x * sc); h0[1] = (short)f2bf(v0.y * sc);
            h0[2] = (short)f2bf(v0.z * sc); h0[3] = (short)f2bf(v0.w * sc);
            h0[4] = (short)f2bf(v1.x * sc); h0[5] = (short)f2bf(v1.y * sc);
            h0[6] = (short)f2bf(v1.z * sc); h0[7] = (short)f2bf(v1.w * sc);
            h1[0] = (short)f2bf(v2.x * sc); h1[1] = (short)f2bf(v2.y * sc);
            h1[2] = (short)f2bf(v2.z * sc); h1[3] = (short)f2bf(v2.w * sc);
            h1[4] = (short)f2bf(v3.x * sc); h1[5] = (short)f2bf(v3.y * sc);
            h1[6] = (short)f2bf(v3.z * sc); h1[7] = (short)f2bf(v3.w * sc);
            *(short8*)&As[row * 32 + half * 16] = h0;
            *(short8*)&As[row * 32 + half * 16 + 8] = h1;
        } else {
            const unsigned short* Ah = (const unsigned short*)A_;
#pragma unroll
            for (int i = 0; i < 2; ++i) {
                int lin = t + i * 256;           // chunk id; wave-contiguous
                int row = lin >> 2, seg = lin & 3;
                async_ld16(Ah + (size_t)(m0 + row) * lda + k0 + seg * 8, &As[lin * 8]);
            }
        }
#pragma unroll
        for (int i = 0; i < 2; ++i) {
            int lin = t + i * 256;
            int row = lin >> 2, seg = lin & 3;
            async_ld16(W + (size_t)(n0 + row) * ldw + k0 + seg * 8, &Bs[lin * 8]);
        }
        __syncthreads();

        short8 af[4], bq[4];
#pragma unroll
        for (int mi = 0; mi < 4; ++mi)
            af[mi] = *(const short8*)&As[(wr * 64 + mi * 16 + lm) * 32 + lg * 8];
#pragma unroll
        for (int ni = 0; ni < 4; ++ni)
            bq[ni] = *(const short8*)&Bs[(wc * 64 + ni * 16 + lm) * 32 + lg * 8];
#pragma unroll
        for (int mi = 0; mi < 4; ++mi)
#pragma unroll
            for (int ni = 0; ni < 4; ++ni)
                acc[mi][ni] = __builtin_amdgcn_mfma_f32_16x16x32_bf16(af[mi], bq[ni], acc[mi][ni], 0, 0, 0);
        __syncthreads();
    }

    // epilogue: C/D frag layout (m89): col = lane&15, row = (lane>>4)*4 + reg
#pragma unroll
    for (int mi = 0; mi < 4; ++mi) {
        int rbase = m0 + wr * 64 + mi * 16 + lg * 4;
#pragma unroll
        for (int ni = 0; ni < 4; ++ni) {
            int n = n0 + wc * 64 + ni * 16 + lm;
            float bv = bias[n];
#pragma unroll
            for (int j = 0; j < 4; ++j) {
                int r = rbase + j;
                float v = acc[mi][ni][j] + bv;
                size_t off = (size_t)r * ldc + n;
                if (MODE == 2) v *= b2f(((const unsigned short*)C_)[off]);
                if (MODE == 3) v *= rowscale[(size_t)(r / NN) * CC + n];
                if (OUTF32) {
                    ((float*)C_)[off] = v;
                } else {
                    unsigned short hv = f2bf(v);
                    ((unsigned short*)C_)[off] = hv;
                    if (DUAL) ((unsigned short*)C2_)[off] = hv;
                }
            }
        }
    }
}

// ---------------------------------------------------------------------------
// small fp32 GEMM for M=128 rows: C[m,n] = epi(sum_k A[m,k]*W[n,k] + bias[n])
// 64x64 tile, BK=32, 256 thr, 4x4 micro. grid (M/64, 8).
// MODE 0: bias; MODE 4: elu(bias)
// ---------------------------------------------------------------------------
template <int MODE>
__global__ __launch_bounds__(256) void gemm_small(
    const float* __restrict__ A, const float* __restrict__ W,
    const float* __restrict__ bias, float* __restrict__ C) {
    __shared__ float As[32 * 72];
    __shared__ float Bs[32 * 72];
    const int t = threadIdx.x;
    const int m0 = blockIdx.x * 64, n0 = blockIdx.y * 64;
    const int tr = t >> 4, tc = t & 15;
    float acc[4][4];
#pragma unroll
    for (int i = 0; i < 4; ++i)
#pragma unroll
        for (int j = 0; j < 4; ++j) acc[i][j] = 0.f;

    for (int k0 = 0; k0 < CC; k0 += 32) {
        int row = t >> 2, seg = t & 3;
        {
            const float* s = A + (size_t)(m0 + row) * CC + k0 + seg * 8;
            float4 v0 = *(const float4*)s, v1 = *(const float4*)(s + 4);
            As[(seg * 8 + 0) * 72 + row] = v0.x; As[(seg * 8 + 1) * 72 + row] = v0.y;
            As[(seg * 8 + 2) * 72 + row] = v0.z; As[(seg * 8 + 3) * 72 + row] = v0.w;
            As[(seg * 8 + 4) * 72 + row] = v1.x; As[(seg * 8 + 5) * 72 + row] = v1.y;
            As[(seg * 8 + 6) * 72 + row] = v1.z; As[(seg * 8 + 7) * 72 + row] = v1.w;
        }
        {
            const float* s = W + (size_t)(n0 + row) * CC + k0 + seg * 8;
            float4 v0 = *(const float4*)s, v1 = *(const float4*)(s + 4);
            Bs[(seg * 8 + 0) * 72 + row] = v0.x; Bs[(seg * 8 + 1) * 72 + row] = v0.y;
            Bs[(seg * 8 + 2) * 72 + row] = v0.z; Bs[(seg * 8 + 3) * 72 + row] = v0.w;
            Bs[(seg * 8 + 4) * 72 + row] = v1.x; Bs[(seg * 8 + 5) * 72 + row] = v1.y;
            Bs[(seg * 8 + 6) * 72 + row] = v1.z; Bs[(seg * 8 + 7) * 72 + row] = v1.w;
        }
        __syncthreads();
#pragma unroll
        for (int kk = 0; kk < 32; ++kk) {
            float4 a = *(const float4*)&As[kk * 72 + tr * 4];
            float4 b = *(const float4*)&Bs[kk * 72 + tc * 4];
            float av[4] = {a.x, a.y, a.z, a.w}, bv[4] = {b.x, b.y, b.z, b.w};
#pragma unroll
            for (int i = 0; i < 4; ++i)
#pragma unroll
                for (int j = 0; j < 4; ++j) acc[i][j] = fmaf(av[i], bv[j], acc[i][j]);
        }
        __syncthreads();
    }
#pragma unroll
    for (int i = 0; i < 4; ++i) {
#pragma unroll
        for (int j = 0; j < 4; ++j) {
            int n = n0 + tc * 4 + j;
            float v = acc[i][j] + bias[n];
            if (MODE == 4) v = v > 0.f ? v : expm1f(v);
            C[(size_t)(m0 + tr * 4 + i) * CC + n] = v;
        }
    }
}

// ---------------------------------------------------------------------------
// Per-batch command extraction (fp32):
//   raw[l] = sum_c qcmd[b,c]*wl[c]*lstm[b,l,c] + bl; att = masked softmax;
//   cmd[b,c] = sum_l att[l]*lstm[b,l,c]
// ---------------------------------------------------------------------------
__global__ __launch_bounds__(256) void cmd_kernel(
    const float* __restrict__ qcmd, const float* __restrict__ lstm,
    const float* __restrict__ wlogit, const float* __restrict__ blogit,
    const int* __restrict__ qlen, float* __restrict__ cmd) {
    const int b = blockIdx.x;
    const int t = threadIdx.x;
    __shared__ float qw[CC];
    __shared__ float att[LL];
    for (int c = t; c < CC; c += 256) qw[c] = qcmd[b * CC + c] * wlogit[c];
    __syncthreads();
    const int wid = t >> 6, lane = t & 63;
    for (int l = wid; l < LL; l += 4) {
        const float* lp = lstm + ((size_t)b * LL + l) * CC;
        float s = 0.f;
        for (int c = lane; c < CC; c += 64) s = fmaf(qw[c], lp[c], s);
#pragma unroll
        for (int off = 32; off > 0; off >>= 1) s += __shfl_down(s, off);
        if (lane == 0) att[l] = s + blogit[0];
    }
    __syncthreads();
    if (t == 0) {
        int Lq = qlen[b];
        float mx = -1e30f;
        for (int l = 0; l < LL; ++l) {
            if (l >= Lq) att[l] = -1e30f;
            mx = fmaxf(mx, att[l]);
        }
        float sum = 0.f;
        for (int l = 0; l < LL; ++l) { float e = expf(att[l] - mx); att[l] = e; sum += e; }
        float inv = 1.f / sum;
        for (int l = 0; l < LL; ++l) att[l] *= inv;
    }
    __syncthreads();
    for (int c = t; c < CC; c += 256) {
        float s = 0.f;
        for (int l = 0; l < LL; ++l) s = fmaf(att[l], lstm[((size_t)b * LL + l) * CC + c], s);
        cmd[b * CC + c] = s;
    }
}

// ---------------------------------------------------------------------------
// Fused attention (bf16 in, bf16 out, fp32 compute): per (b, q-half):
// S = Q Kt / sqrt(C); masked softmax over k; msg = P V (written into
// x_joint prod column, stride XJLD). grid (128, 2), block 256.
// ---------------------------------------------------------------------------
__global__ __launch_bounds__(256) void attn_kernel(
    const unsigned short* __restrict__ Qm, const unsigned short* __restrict__ Km,
    const unsigned short* __restrict__ Vm, const int* __restrict__ entnum,
    unsigned short* __restrict__ msg) {
    __shared__ float S[QH * NN];      // 5000 floats; first 50*65 alias the Q chunk buf
    __shared__ float Bbuf[NN * 65];   // K / V chunk, padded
    float* Abuf = S;                  // [QH][65] during phase A only
    const int b = blockIdx.x;
    const int qbase = blockIdx.y * QH;
    const int t = threadIdx.x;
    const int tq = t >> 4, tk = t & 15;
    const unsigned short* Qp = Qm + ((size_t)b * NN + qbase) * CC;
    const unsigned short* Kp = Km + (size_t)b * NN * CC;
    const unsigned short* Vp = Vm + (size_t)b * NN * CC;

    float acc[4][7];
#pragma unroll
    for (int i = 0; i < 4; ++i)
#pragma unroll
        for (int j = 0; j < 7; ++j) acc[i][j] = 0.f;

    // ---- phase A: scores ----
    for (int c0 = 0; c0 < CC; c0 += 64) {
        for (int lin = t; lin < QH * 64; lin += 256) {
            int row = lin >> 6, col = lin & 63;
            Abuf[row * 65 + col] = b2f(Qp[(size_t)row * CC + c0 + col]);
        }
        for (int lin = t; lin < NN * 64; lin += 256) {
            int row = lin >> 6, col = lin & 63;
            Bbuf[row * 65 + col] = b2f(Kp[(size_t)row * CC + c0 + col]);
        }
        __syncthreads();
#pragma unroll 8
        for (int kk = 0; kk < 64; ++kk) {
            float a[4], bb[7];
#pragma unroll
            for (int i = 0; i < 4; ++i) { int q = tq + 16 * i; a[i] = (q < QH) ? Abuf[q * 65 + kk] : 0.f; }
#pragma unroll
            for (int j = 0; j < 7; ++j) { int k = tk + 16 * j; bb[j] = (k < NN) ? Bbuf[k * 65 + kk] : 0.f; }
#pragma unroll
            for (int i = 0; i < 4; ++i)
#pragma unroll
                for (int j = 0; j < 7; ++j) acc[i][j] = fmaf(a[i], bb[j], acc[i][j]);
        }
        __syncthreads();
    }
#pragma unroll
    for (int i = 0; i < 4; ++i) {
        int q = tq + 16 * i;
        if (q < QH) {
#pragma unroll
            for (int j = 0; j < 7; ++j) {
                int k = tk + 16 * j;
                if (k < NN) S[q * NN + k] = acc[i][j] * INV_SQRT_C_F;
            }
        }
    }
    __syncthreads();

    // ---- phase B: masked softmax over k ----
    const int en = entnum[b];
    const int wid = t >> 6, lane = t & 63;
    for (int q = wid; q < QH; q += 4) {
        float v0 = (lane < en) ? S[q * NN + lane] : -1e30f;
        int k1 = lane + 64;
        float v1 = (k1 < NN && k1 < en) ? S[q * NN + k1] : -1e30f;
        float mx = fmaxf(v0, v1);
#pragma unroll
        for (int o = 32; o > 0; o >>= 1) mx = fmaxf(mx, __shfl_xor(mx, o));
        float e0 = expf(v0 - mx), e1 = expf(v1 - mx);
        float ss = e0 + e1;
#pragma unroll
        for (int o = 32; o > 0; o >>= 1) ss += __shfl_xor(ss, o);
        float inv = 1.f / ss;
        if (lane < NN) S[q * NN + lane] = e0 * inv;
        if (k1 < NN) S[q * NN + k1] = e1 * inv;
    }
    __syncthreads();

    // ---- phase C: msg = P V ----
    const int tcc = t & 63, tqq = t >> 6;
    for (int c0 = 0; c0 < CC; c0 += 64) {
        for (int lin = t; lin < NN * 64; lin += 256) {
            int row = lin >> 6, col = lin & 63;
            Bbuf[row * 65 + col] = b2f(Vp[(size_t)row * CC + c0 + col]);
        }
        __syncthreads();
        for (int q = tqq; q < QH; q += 4) {
            float s = 0.f;
#pragma unroll 4
            for (int k = 0; k < NN; ++k) s = fmaf(S[q * NN + k], Bbuf[k * 65 + tcc], s);
            msg[((size_t)b * NN + qbase + q) * XJLD + c0 + tcc] = f2bf(s);
        }
        __syncthreads();
    }
}

// ---------------------------------------------------------------------------
extern "C" void kernel_launch(void* const* d_in, const int* in_sizes, int n_in,
                              void* d_out, int out_size, void* d_ws, size_t ws_size,
                              hipStream_t stream) {
    const float* images   = (const float*)d_in[0];
    const float* q_enc    = (const float*)d_in[1];
    const float* lstm     = (const float*)d_in[2];
    const float* W_initKB = (const float*)d_in[3];
    const float* b_initKB = (const float*)d_in[4];
    const float* initMem  = (const float*)d_in[5];
    const float* W_qIn    = (const float*)d_in[6];
    const float* b_qIn    = (const float*)d_in[7];
    const float* W_qIn2   = (const float*)d_in[8];
    const float* b_qIn2   = (const float*)d_in[9];
    const float* W_logit  = (const float*)d_in[10];
    const float* b_logit  = (const float*)d_in[11];
    const float* W_ploc   = (const float*)d_in[12];
    const float* b_ploc   = (const float*)d_in[13];
    const float* W_pctx   = (const float*)d_in[14];
    const float* b_pctx   = (const float*)d_in[15];
    const float* W_q      = (const float*)d_in[16];
    const float* b_q      = (const float*)d_in[17];
    const float* W_k      = (const float*)d_in[18];
    const float* b_k      = (const float*)d_in[19];
    const float* W_v      = (const float*)d_in[20];
    const float* b_v      = (const float*)d_in[21];
    const float* W_pk     = (const float*)d_in[22];
    const float* b_pk     = (const float*)d_in[23];
    const float* W_pv     = (const float*)d_in[24];
    const float* b_pv     = (const float*)d_in[25];
    const float* W_mem    = (const float*)d_in[26];
    const float* b_mem    = (const float*)d_in[27];
    const float* W_comb   = (const float*)d_in[28];
    const float* b_comb   = (const float*)d_in[29];
    const int* q_length   = (const int*)d_in[30];
    const int* entity_num = (const int*)d_in[31];
    (void)in_sizes; (void)n_in; (void)out_size; (void)ws_size;

    // ---- workspace carve ----
    char* p = (char*)d_ws;
    auto alloc = [&](size_t bytes) { char* q = p; p += (bytes + 255) & ~(size_t)255; return q; };
    unsigned short* XJ0 = (unsigned short*)alloc((size_t)ROWS * XJLD * 2);
    unsigned short* XJ1 = (unsigned short*)alloc((size_t)ROWS * XJLD * 2);
    unsigned short* Qb  = (unsigned short*)alloc((size_t)ROWS * CC * 2);
    unsigned short* Kb  = (unsigned short*)alloc((size_t)ROWS * CC * 2);
    unsigned short* Vb  = (unsigned short*)alloc((size_t)ROWS * CC * 2);
    unsigned short* Wbf = (unsigned short*)alloc((size_t)5013504 * 2);
    float* qcb  = (float*)alloc((size_t)BB * CC * 4);
    float* qcmd = (float*)alloc((size_t)BB * CC * 4);
    float* cmd  = (float*)alloc((size_t)BB * CC * 4);
    float* pk   = (float*)alloc((size_t)BB * CC * 4);
    float* pv   = (float*)alloc((size_t)BB * CC * 4);
    float* invn = (float*)alloc((size_t)ROWS * 4);

    // bf16 weight offsets (elements)
    unsigned short* Wi_init = Wbf + 0;
    unsigned short* Wi_ploc = Wbf + 1081344;
    unsigned short* Wi_pctx = Wbf + 1343488;
    unsigned short* Wi_q    = Wbf + 1605632;
    unsigned short* Wi_k    = Wbf + 2392064;
    unsigned short* Wi_v    = Wbf + 3178496;
    unsigned short* Wi_mem  = Wbf + 3964928;
    unsigned short* Wi_comb = Wbf + 4489216;

    auto cvt = [&](const float* src, unsigned short* dst, size_t n) {
        int n4 = (int)(n / 4);
        cvt_kernel<<<dim3((n4 + 255) / 256), dim3(256), 0, stream>>>(src, dst, n4);
    };

    // ---- stem ----
    rownorm_kernel<<<dim3(ROWS), dim3(256), 0, stream>>>(images, invn);
    cvt(W_initKB, Wi_init, (size_t)CC * DFEAT);
    cvt(W_ploc,  Wi_ploc, (size_t)CC * CC);
    cvt(W_pctx,  Wi_pctx, (size_t)CC * CC);
    cvt(W_q,     Wi_q,    (size_t)CC * 3 * CC);
    cvt(W_k,     Wi_k,    (size_t)CC * 3 * CC);
    cvt(W_v,     Wi_v,    (size_t)CC * 3 * CC);
    cvt(W_mem,   Wi_mem,  (size_t)CC * 2 * CC);
    cvt(W_comb,  Wi_comb, (size_t)CC * 2 * CC);

    dim3 gBig(ROWS / 128, 4), blk(256);
    // x_loc = norm(images) @ W_initKB.T + b  -> XJ0 col 0 and XJ1 col 0 (bf16)
    gemm_mfma<0, true, false, true><<<gBig, blk, 0, stream>>>(
        images, DFEAT, Wi_init, DFEAT, b_initKB, XJ0, XJLD, XJ1, DFEAT, invn, nullptr);
    bcast_kernel<<<dim3((ROWS * CC + 255) / 256), dim3(256), 0, stream>>>(initMem, XJ0);
    gemm_small<4><<<dim3(BB / 64, 8), blk, 0, stream>>>(q_enc, W_qIn, b_qIn, qcb);

    for (int t = 0; t < TT; ++t) {
        unsigned short* R  = (t & 1) ? XJ1 : XJ0;   // read buffer
        unsigned short* Wr = (t & 1) ? XJ0 : XJ1;   // write buffer (next x_ctx)
        // textual command
        gemm_small<0><<<dim3(BB / 64, 8), blk, 0, stream>>>(
            qcb, W_qIn2 + (size_t)t * CC * CC, b_qIn2 + (size_t)t * CC, qcmd);
        cmd_kernel<<<dim3(BB), blk, 0, stream>>>(qcmd, lstm, W_logit, b_logit, q_length, cmd);
        gemm_small<0><<<dim3(BB / 64, 8), blk, 0, stream>>>(cmd, W_pk, b_pk, pk);
        gemm_small<0><<<dim3(BB / 64, 8), blk, 0, stream>>>(cmd, W_pv, b_pv, pv);
        // prod = (x_loc@Wploc+b) * (xc@Wpctx+b)  -> R col 1024
        gemm_mfma<0, false, false, false><<<gBig, blk, 0, stream>>>(
            R, XJLD, Wi_ploc, CC, b_ploc, R + 2 * CC, XJLD, nullptr, CC, nullptr, nullptr);
        gemm_mfma<2, false, false, false><<<gBig, blk, 0, stream>>>(
            R + CC, XJLD, Wi_pctx, CC, b_pctx, R + 2 * CC, XJLD, nullptr, CC, nullptr, nullptr);
        // Q/K/V over x_joint (K=1536)
        gemm_mfma<0, false, false, false><<<gBig, blk, 0, stream>>>(
            R, XJLD, Wi_q, 3 * CC, b_q, Qb, CC, nullptr, 3 * CC, nullptr, nullptr);
        gemm_mfma<3, false, false, false><<<gBig, blk, 0, stream>>>(
            R, XJLD, Wi_k, 3 * CC, b_k, Kb, CC, nullptr, 3 * CC, nullptr, pk);
        gemm_mfma<3, false, false, false><<<gBig, blk, 0, stream>>>(
            R, XJLD, Wi_v, 3 * CC, b_v, Vb, CC, nullptr, 3 * CC, nullptr, pv);
        // attention -> message into R col 1024 (prod dead now)
        attn_kernel<<<dim3(BB, 2), blk, 0, stream>>>(Qb, Kb, Vb, entity_num, R + 2 * CC);
        // x_ctx_new = [xc | message] @ W_mem.T + b  -> Wr col 512
        gemm_mfma<0, false, false, false><<<gBig, blk, 0, stream>>>(
            R + CC, XJLD, Wi_mem, 2 * CC, b_mem, Wr + CC, XJLD, nullptr, 2 * CC, nullptr, nullptr);
    }
    // output = [x_loc | x_ctx] @ W_comb.T + b  (x_ctx final is in XJ0 col 512)
    gemm_mfma<0, false, true, false><<<gBig, blk, 0, stream>>>(
        XJ0, XJLD, Wi_comb, 2 * CC, b_comb, (float*)d_out, CC, nullptr, 2 * CC, nullptr, nullptr);
}

// Round 5
// 1708.068 us; speedup vs baseline: 4.6130x; 1.4897x over previous
//
#include <hip/hip_runtime.h>
#include <math.h>

#define BB 128
#define NN 100
#define LL 30
#define CC 512
#define DFEAT 2112
#define TT 4
#define ROWS (BB * NN)          // 12800
#define XJLD 1536               // x_joint row stride (bf16): [x_loc | x_ctx | prod]
#define INV_SQRT_C_F 0.04419417382415922f
#define QH 50                    // q-rows per attention block (2 halves)
#define VTK 128                  // Vt padded K (attention positions)

typedef __attribute__((ext_vector_type(8))) short short8;
typedef __attribute__((ext_vector_type(4))) float f32x4;

__device__ inline unsigned short f2bf(float f) {
    unsigned u = __float_as_uint(f);
    u += 0x7fff + ((u >> 16) & 1);          // round-to-nearest-even
    return (unsigned short)(u >> 16);
}
__device__ inline float b2f(unsigned short h) { return __uint_as_float((unsigned)h << 16); }

__device__ inline void async_ld16(const unsigned short* g, unsigned short* l) {
    __builtin_amdgcn_global_load_lds((const __attribute__((address_space(1))) void*)g,
                                     (__attribute__((address_space(3))) void*)l, 16, 0, 0);
}

// ---------------------------------------------------------------------------
// inv_norm[r] = 1 / max(||images[r,:]||, 1e-12)
// ---------------------------------------------------------------------------
__global__ __launch_bounds__(256) void rownorm_kernel(const float* __restrict__ img,
                                                      float* __restrict__ inv_norm) {
    int r = blockIdx.x;
    const float* p = img + (size_t)r * DFEAT;
    float s = 0.f;
    for (int i = threadIdx.x; i < DFEAT; i += 256) { float v = p[i]; s += v * v; }
    __shared__ float red[4];
    int lane = threadIdx.x & 63, wid = threadIdx.x >> 6;
#pragma unroll
    for (int off = 32; off > 0; off >>= 1) s += __shfl_down(s, off);
    if (lane == 0) red[wid] = s;
    __syncthreads();
    if (threadIdx.x == 0) {
        float tot = red[0] + red[1] + red[2] + red[3];
        inv_norm[r] = 1.f / fmaxf(sqrtf(tot), 1e-12f);
    }
}

// ---------------------------------------------------------------------------
// fp32 -> bf16 weight conversion (vectorized, n4 = n/4)
// ---------------------------------------------------------------------------
__global__ __launch_bounds__(256) void cvt_kernel(const float* __restrict__ s,
                                                  unsigned short* __restrict__ d, int n4) {
    int i = blockIdx.x * blockDim.x + threadIdx.x;
    if (i < n4) {
        float4 v = ((const float4*)s)[i];
        ushort4 o;
        o.x = f2bf(v.x); o.y = f2bf(v.y); o.z = f2bf(v.z); o.w = f2bf(v.w);
        ((ushort4*)d)[i] = o;
    }
}

__global__ void zero16_kernel(uint4* __restrict__ p, int n) {
    int i = blockIdx.x * blockDim.x + threadIdx.x;
    if (i < n) p[i] = uint4{0u, 0u, 0u, 0u};
}

// ---------------------------------------------------------------------------
// broadcast initMem[512] (fp32) into XJ0 x_ctx column (bf16, stride XJLD)
// ---------------------------------------------------------------------------
__global__ void bcast_kernel(const float* __restrict__ m, unsigned short* __restrict__ x) {
    int i = blockIdx.x * blockDim.x + threadIdx.x;
    if (i < ROWS * CC) {
        int r = i >> 9, c = i & (CC - 1);
        x[(size_t)r * XJLD + CC + c] = f2bf(m[c]);
    }
}

// ---------------------------------------------------------------------------
// MFMA GEMM: C[m,n] = epi( sum_k A[m,k] * W[n,k] )  -- W row-major [512][ldw] bf16
// tile 128x128, BK=32, 4 waves each owning a 64x64 quadrant (4x4 frags of
// 16x16x32 bf16 MFMA). N fixed 512 (grid.y = 4), M = grid.x*128.
// MODE 0: v = acc + bias[n]
// MODE 2: v = (acc + bias[n]) * C_prev   (proj_loc * proj_ctx, in-place on C)
// MODE 3: v = (acc + bias[n]) * rowscale[(r/100)*512 + n]
// AF32: A is fp32 (stem; reg-staged with optional row scale arsc), else bf16
//       staged via global_load_lds width-16.
// OUTF32: write fp32 (d_out), else bf16.  DUAL: also write C2 (stem).
// VT: write transposed per-batch layout Vt[b][n][VTK] (attention V operand).
// ---------------------------------------------------------------------------
template <int MODE, bool AF32, bool OUTF32, bool DUAL, bool VT>
__global__ __launch_bounds__(256) void gemm_mfma(
    const void* __restrict__ A_, int lda,
    const unsigned short* __restrict__ W, int ldw,
    const float* __restrict__ bias,
    void* __restrict__ C_, int ldc,
    void* __restrict__ C2_,
    int K,
    const float* __restrict__ arsc,
    const float* __restrict__ rowscale) {
    __shared__ unsigned short As[128 * 32];
    __shared__ unsigned short Bs[128 * 32];
    const int t = threadIdx.x;
    const int l = t & 63;
    const int wv = t >> 6;
    const int wr = wv >> 1, wc = wv & 1;
    const int lg = l >> 4, lm = l & 15;
    const int m0 = blockIdx.x * 128, n0 = blockIdx.y * 128;

    f32x4 acc[4][4];
#pragma unroll
    for (int mi = 0; mi < 4; ++mi)
#pragma unroll
        for (int ni = 0; ni < 4; ++ni) acc[mi][ni] = {0.f, 0.f, 0.f, 0.f};

    for (int k0 = 0; k0 < K; k0 += 32) {
        if (AF32) {
            // reg-stage fp32 A -> bf16 LDS (row-major [128][32])
            const float* Af = (const float*)A_;
            int row = t >> 1, half = t & 1;
            const float* s = Af + (size_t)(m0 + row) * lda + k0 + half * 16;
            float sc = arsc ? arsc[m0 + row] : 1.f;
            float4 v0 = *(const float4*)s, v1 = *(const float4*)(s + 4);
            float4 v2 = *(const float4*)(s + 8), v3 = *(const float4*)(s + 12);
            short8 h0, h1;
            h0[0] = (short)f2bf(v0.x * sc); h0[1] = (short)f2bf(v0.y * sc);
            h0[2] = (short)f2bf(v0.z * sc); h0[3] = (short)f2bf(v0.w * sc);
            h0[4] = (short)f2bf(v1.x * sc); h0[5] = (short)f2bf(v1.y * sc);
            h0[6] = (short)f2bf(v1.z * sc); h0[7] = (short)f2bf(v1.w * sc);
            h1[0] = (short)f2bf(v2.x * sc); h1[1] = (short)f2bf(v2.y * sc);
            h1[2] = (short)f2bf(v2.z * sc); h1[3] = (short)f2bf(v2.w * sc);
            h1[4] = (short)f2bf(v3.x * sc); h1[5] = (short)f2bf(v3.y * sc);
            h1[6] = (short)f2bf(v3.z * sc); h1[7] = (short)f2bf(v3.w * sc);
            *(short8*)&As[row * 32 + half * 16] = h0;
            *(short8*)&As[row * 32 + half * 16 + 8] = h1;
        } else {
            const unsigned short* Ah = (const unsigned short*)A_;
#pragma unroll
            for (int i = 0; i < 2; ++i) {
                int lin = t + i * 256;           // chunk id; wave-contiguous
                int row = lin >> 2, seg = lin & 3;
                async_ld16(Ah + (size_t)(m0 + row) * lda + k0 + seg * 8, &As[lin * 8]);
            }
        }
#pragma unroll
        for (int i = 0; i < 2; ++i) {
            int lin = t + i * 256;
            int row = lin >> 2, seg = lin & 3;
            async_ld16(W + (size_t)(n0 + row) * ldw + k0 + seg * 8, &Bs[lin * 8]);
        }
        __syncthreads();

        short8 af[4], bq[4];
#pragma unroll
        for (int mi = 0; mi < 4; ++mi)
            af[mi] = *(const short8*)&As[(wr * 64 + mi * 16 + lm) * 32 + lg * 8];
#pragma unroll
        for (int ni = 0; ni < 4; ++ni)
            bq[ni] = *(const short8*)&Bs[(wc * 64 + ni * 16 + lm) * 32 + lg * 8];
#pragma unroll
        for (int mi = 0; mi < 4; ++mi)
#pragma unroll
            for (int ni = 0; ni < 4; ++ni)
                acc[mi][ni] = __builtin_amdgcn_mfma_f32_16x16x32_bf16(af[mi], bq[ni], acc[mi][ni], 0, 0, 0);
        __syncthreads();
    }

    // epilogue: C/D frag layout (m89): col = lane&15, row = (lane>>4)*4 + reg
#pragma unroll
    for (int mi = 0; mi < 4; ++mi) {
        int rbase = m0 + wr * 64 + mi * 16 + lg * 4;
#pragma unroll
        for (int ni = 0; ni < 4; ++ni) {
            int n = n0 + wc * 64 + ni * 16 + lm;
            float bv = bias[n];
#pragma unroll
            for (int j = 0; j < 4; ++j) {
                int r = rbase + j;
                float v = acc[mi][ni][j] + bv;
                size_t off = (size_t)r * ldc + n;
                if (MODE == 2) v *= b2f(((const unsigned short*)C_)[off]);
                if (MODE == 3) v *= rowscale[(size_t)(r / NN) * CC + n];
                if (OUTF32) {
                    ((float*)C_)[off] = v;
                } else {
                    unsigned short hv = f2bf(v);
                    if (VT) {
                        int b2 = r / NN, rl = r - b2 * NN;
                        ((unsigned short*)C_)[((size_t)b2 * CC + n) * VTK + rl] = hv;
                    } else {
                        ((unsigned short*)C_)[off] = hv;
                        if (DUAL) ((unsigned short*)C2_)[off] = hv;
                    }
                }
            }
        }
    }
}

// ---------------------------------------------------------------------------
// small fp32 GEMM for M=128 rows: C[m,n] = epi(sum_k A[m,k]*W[n,k] + bias[n])
// 64x64 tile, BK=32, 256 thr, 4x4 micro. grid (M/64, 8).
// MODE 0: bias; MODE 4: elu(bias)
// ---------------------------------------------------------------------------
template <int MODE>
__global__ __launch_bounds__(256) void gemm_small(
    const float* __restrict__ A, const float* __restrict__ W,
    const float* __restrict__ bias, float* __restrict__ C) {
    __shared__ float As[32 * 72];
    __shared__ float Bs[32 * 72];
    const int t = threadIdx.x;
    const int m0 = blockIdx.x * 64, n0 = blockIdx.y * 64;
    const int tr = t >> 4, tc = t & 15;
    float acc[4][4];
#pragma unroll
    for (int i = 0; i < 4; ++i)
#pragma unroll
        for (int j = 0; j < 4; ++j) acc[i][j] = 0.f;

    for (int k0 = 0; k0 < CC; k0 += 32) {
        int row = t >> 2, seg = t & 3;
        {
            const float* s = A + (size_t)(m0 + row) * CC + k0 + seg * 8;
            float4 v0 = *(const float4*)s, v1 = *(const float4*)(s + 4);
            As[(seg * 8 + 0) * 72 + row] = v0.x; As[(seg * 8 + 1) * 72 + row] = v0.y;
            As[(seg * 8 + 2) * 72 + row] = v0.z; As[(seg * 8 + 3) * 72 + row] = v0.w;
            As[(seg * 8 + 4) * 72 + row] = v1.x; As[(seg * 8 + 5) * 72 + row] = v1.y;
            As[(seg * 8 + 6) * 72 + row] = v1.z; As[(seg * 8 + 7) * 72 + row] = v1.w;
        }
        {
            const float* s = W + (size_t)(n0 + row) * CC + k0 + seg * 8;
            float4 v0 = *(const float4*)s, v1 = *(const float4*)(s + 4);
            Bs[(seg * 8 + 0) * 72 + row] = v0.x; Bs[(seg * 8 + 1) * 72 + row] = v0.y;
            Bs[(seg * 8 + 2) * 72 + row] = v0.z; Bs[(seg * 8 + 3) * 72 + row] = v0.w;
            Bs[(seg * 8 + 4) * 72 + row] = v1.x; Bs[(seg * 8 + 5) * 72 + row] = v1.y;
            Bs[(seg * 8 + 6) * 72 + row] = v1.z; Bs[(seg * 8 + 7) * 72 + row] = v1.w;
        }
        __syncthreads();
#pragma unroll
        for (int kk = 0; kk < 32; ++kk) {
            float4 a = *(const float4*)&As[kk * 72 + tr * 4];
            float4 b = *(const float4*)&Bs[kk * 72 + tc * 4];
            float av[4] = {a.x, a.y, a.z, a.w}, bv[4] = {b.x, b.y, b.z, b.w};
#pragma unroll
            for (int i = 0; i < 4; ++i)
#pragma unroll
                for (int j = 0; j < 4; ++j) acc[i][j] = fmaf(av[i], bv[j], acc[i][j]);
        }
        __syncthreads();
    }
#pragma unroll
    for (int i = 0; i < 4; ++i) {
#pragma unroll
        for (int j = 0; j < 4; ++j) {
            int n = n0 + tc * 4 + j;
            float v = acc[i][j] + bias[n];
            if (MODE == 4) v = v > 0.f ? v : expm1f(v);
            C[(size_t)(m0 + tr * 4 + i) * CC + n] = v;
        }
    }
}

// ---------------------------------------------------------------------------
// Per-batch command extraction (fp32)
// ---------------------------------------------------------------------------
__global__ __launch_bounds__(256) void cmd_kernel(
    const float* __restrict__ qcmd, const float* __restrict__ lstm,
    const float* __restrict__ wlogit, const float* __restrict__ blogit,
    const int* __restrict__ qlen, float* __restrict__ cmd) {
    const int b = blockIdx.x;
    const int t = threadIdx.x;
    __shared__ float qw[CC];
    __shared__ float att[LL];
    for (int c = t; c < CC; c += 256) qw[c] = qcmd[b * CC + c] * wlogit[c];
    __syncthreads();
    const int wid = t >> 6, lane = t & 63;
    for (int l = wid; l < LL; l += 4) {
        const float* lp = lstm + ((size_t)b * LL + l) * CC;
        float s = 0.f;
        for (int c = lane; c < CC; c += 64) s = fmaf(qw[c], lp[c], s);
#pragma unroll
        for (int off = 32; off > 0; off >>= 1) s += __shfl_down(s, off);
        if (lane == 0) att[l] = s + blogit[0];
    }
    __syncthreads();
    if (t == 0) {
        int Lq = qlen[b];
        float mx = -1e30f;
        for (int l = 0; l < LL; ++l) {
            if (l >= Lq) att[l] = -1e30f;
            mx = fmaxf(mx, att[l]);
        }
        float sum = 0.f;
        for (int l = 0; l < LL; ++l) { float e = expf(att[l] - mx); att[l] = e; sum += e; }
        float inv = 1.f / sum;
        for (int l = 0; l < LL; ++l) att[l] *= inv;
    }
    __syncthreads();
    for (int c = t; c < CC; c += 256) {
        float s = 0.f;
        for (int l = 0; l < LL; ++l) s = fmaf(att[l], lstm[((size_t)b * LL + l) * CC + c], s);
        cmd[b * CC + c] = s;
    }
}

// ---------------------------------------------------------------------------
// MFMA fused attention: per (b, q-half).
//   M = 64 rows (50 valid), K-att = 112 staged / 128 padded, C = 512.
//   Phase A: S = Q K^T / sqrt(C) via 16x16x32 MFMA, BK=64 LDS staging.
//   Phase B: masked softmax rows<50, cols<en; cols [en,128) zeroed.
//   Phase C: msg = P V via MFMA; P from LDS (bf16-cvt), V from global Vt
//            (Vt[b][n][VTK], zero-padded k>=100 so pad contributes exact 0).
// Padding rows/cols compute garbage but MFMA is row/col-local; garbage rows
// are never written, garbage cols never read (en <= 100).
// grid (BB, 2), block 256 (4 waves).
// ---------------------------------------------------------------------------
__global__ __launch_bounds__(256) void attn_mfma_kernel(
    const unsigned short* __restrict__ Qm, const unsigned short* __restrict__ Km,
    const unsigned short* __restrict__ Vt, const int* __restrict__ entnum,
    unsigned short* __restrict__ msg) {
    __shared__ char ldsraw[64 * 132 * 4];      // 33792 B
    float* S = (float*)ldsraw;                 // [64][132] fp32 (phase B/C)
    unsigned short* Qs = (unsigned short*)ldsraw;            // [64][64] bf16 (phase A)
    unsigned short* Ks = (unsigned short*)(ldsraw + 8192);   // [112][64] bf16 (phase A)
    const int b = blockIdx.x;
    const int qbase = blockIdx.y * QH;
    const int t = threadIdx.x;
    const int wv = t >> 6, l = t & 63, lg = l >> 4, lm = l & 15;
    const unsigned short* Qp = Qm + ((size_t)b * NN + qbase) * CC;
    const unsigned short* Kp = Km + (size_t)b * NN * CC;

    // ---- phase A: scores (each wave owns 16 M-rows x 112 cols) ----
    f32x4 sacc[7];
#pragma unroll
    for (int i = 0; i < 7; ++i) sacc[i] = {0.f, 0.f, 0.f, 0.f};

    for (int k0 = 0; k0 < CC; k0 += 64) {
#pragma unroll
        for (int i = 0; i < 2; ++i) {          // Qs: 512 chunks
            int lin = t + i * 256;
            int row = lin >> 3, seg = lin & 7;
            async_ld16(Qp + (size_t)row * CC + k0 + seg * 8, &Qs[lin * 8]);
        }
#pragma unroll
        for (int i = 0; i < 4; ++i) {          // Ks: 896 chunks (wave-uniform tail)
            int lin = t + i * 256;
            if (lin < 896) {
                int row = lin >> 3, seg = lin & 7;
                async_ld16(Kp + (size_t)row * CC + k0 + seg * 8, &Ks[lin * 8]);
            }
        }
        __syncthreads();
#pragma unroll
        for (int kk = 0; kk < 64; kk += 32) {
            short8 a = *(const short8*)&Qs[(wv * 16 + lm) * 64 + kk + lg * 8];
#pragma unroll
            for (int nf = 0; nf < 7; ++nf) {
                short8 bb = *(const short8*)&Ks[(nf * 16 + lm) * 64 + kk + lg * 8];
                sacc[nf] = __builtin_amdgcn_mfma_f32_16x16x32_bf16(a, bb, sacc[nf], 0, 0, 0);
            }
        }
        __syncthreads();
    }
#pragma unroll
    for (int nf = 0; nf < 7; ++nf)
#pragma unroll
        for (int j = 0; j < 4; ++j)
            S[(wv * 16 + lg * 4 + j) * 132 + nf * 16 + lm] = sacc[nf][j] * INV_SQRT_C_F;
    __syncthreads();

    // ---- phase B: masked softmax (rows 0..49); zero cols [en,128) ----
    const int en = entnum[b];
    for (int q = wv; q < QH; q += 4) {
        float v0 = (l < en) ? S[q * 132 + l] : -1e30f;
        int k1 = l + 64;
        float v1 = (k1 < en) ? S[q * 132 + k1] : -1e30f;
        float mx = fmaxf(v0, v1);
#pragma unroll
        for (int o = 32; o > 0; o >>= 1) mx = fmaxf(mx, __shfl_xor(mx, o));
        float e0 = (l < en) ? expf(v0 - mx) : 0.f;
        float e1 = (k1 < en) ? expf(v1 - mx) : 0.f;
        float ss = e0 + e1;
#pragma unroll
        for (int o = 32; o > 0; o >>= 1) ss += __shfl_xor(ss, o);
        float inv = 1.f / ss;
        S[q * 132 + l] = e0 * inv;
        S[q * 132 + k1] = e1 * inv;
    }
    __syncthreads();

    // ---- phase C: msg = P V (waves split N: wave wv owns cols wv*128..+127) ----
    f32x4 acc[4][8];
#pragma unroll
    for (int mf = 0; mf < 4; ++mf)
#pragma unroll
        for (int nf = 0; nf < 8; ++nf) acc[mf][nf] = {0.f, 0.f, 0.f, 0.f};

    const unsigned short* Vb = Vt + (size_t)b * CC * VTK;
    for (int ks = 0; ks < 4; ++ks) {
        int k0 = ks * 32;
        short8 pa[4];
#pragma unroll
        for (int mf = 0; mf < 4; ++mf) {
            const float* sp = &S[(mf * 16 + lm) * 132 + k0 + lg * 8];
            short8 h;
#pragma unroll
            for (int jj = 0; jj < 8; ++jj) h[jj] = (short)f2bf(sp[jj]);
            pa[mf] = h;
        }
#pragma unroll
        for (int nf = 0; nf < 8; ++nf) {
            short8 bb = *(const short8*)(Vb + ((size_t)(wv * 128 + nf * 16 + lm)) * VTK + k0 + lg * 8);
#pragma unroll
            for (int mf = 0; mf < 4; ++mf)
                acc[mf][nf] = __builtin_amdgcn_mfma_f32_16x16x32_bf16(pa[mf], bb, acc[mf][nf], 0, 0, 0);
        }
    }
    // epilogue: rows q < 50 only
#pragma unroll
    for (int mf = 0; mf < 4; ++mf) {
#pragma unroll
        for (int j = 0; j < 4; ++j) {
            int q = mf * 16 + lg * 4 + j;
            if (q < QH) {
                size_t rb = ((size_t)b * NN + qbase + q) * XJLD;
#pragma unroll
                for (int nf = 0; nf < 8; ++nf)
                    msg[rb + wv * 128 + nf * 16 + lm] = f2bf(acc[mf][nf][j]);
            }
        }
    }
}

// ---------------------------------------------------------------------------
extern "C" void kernel_launch(void* const* d_in, const int* in_sizes, int n_in,
                              void* d_out, int out_size, void* d_ws, size_t ws_size,
                              hipStream_t stream) {
    const float* images   = (const float*)d_in[0];
    const float* q_enc    = (const float*)d_in[1];
    const float* lstm     = (const float*)d_in[2];
    const float* W_initKB = (const float*)d_in[3];
    const float* b_initKB = (const float*)d_in[4];
    const float* initMem  = (const float*)d_in[5];
    const float* W_qIn    = (const float*)d_in[6];
    const float* b_qIn    = (const float*)d_in[7];
    const float* W_qIn2   = (const float*)d_in[8];
    const float* b_qIn2   = (const float*)d_in[9];
    const float* W_logit  = (const float*)d_in[10];
    const float* b_logit  = (const float*)d_in[11];
    const float* W_ploc   = (const float*)d_in[12];
    const float* b_ploc   = (const float*)d_in[13];
    const float* W_pctx   = (const float*)d_in[14];
    const float* b_pctx   = (const float*)d_in[15];
    const float* W_q      = (const float*)d_in[16];
    const float* b_q      = (const float*)d_in[17];
    const float* W_k      = (const float*)d_in[18];
    const float* b_k      = (const float*)d_in[19];
    const float* W_v      = (const float*)d_in[20];
    const float* b_v      = (const float*)d_in[21];
    const float* W_pk     = (const float*)d_in[22];
    const float* b_pk     = (const float*)d_in[23];
    const float* W_pv     = (const float*)d_in[24];
    const float* b_pv     = (const float*)d_in[25];
    const float* W_mem    = (const float*)d_in[26];
    const float* b_mem    = (const float*)d_in[27];
    const float* W_comb   = (const float*)d_in[28];
    const float* b_comb   = (const float*)d_in[29];
    const int* q_length   = (const int*)d_in[30];
    const int* entity_num = (const int*)d_in[31];
    (void)in_sizes; (void)n_in; (void)out_size; (void)ws_size;

    // ---- workspace carve ----
    char* p = (char*)d_ws;
    auto alloc = [&](size_t bytes) { char* q = p; p += (bytes + 255) & ~(size_t)255; return q; };
    unsigned short* XJ0 = (unsigned short*)alloc((size_t)ROWS * XJLD * 2);
    unsigned short* XJ1 = (unsigned short*)alloc((size_t)ROWS * XJLD * 2);
    unsigned short* Qb  = (unsigned short*)alloc((size_t)ROWS * CC * 2);
    unsigned short* Kb  = (unsigned short*)alloc((size_t)ROWS * CC * 2);
    unsigned short* Vt  = (unsigned short*)alloc((size_t)BB * CC * VTK * 2);
    unsigned short* Wbf = (unsigned short*)alloc((size_t)5013504 * 2);
    float* qcb  = (float*)alloc((size_t)BB * CC * 4);
    float* qcmd = (float*)alloc((size_t)BB * CC * 4);
    float* cmd  = (float*)alloc((size_t)BB * CC * 4);
    float* pk   = (float*)alloc((size_t)BB * CC * 4);
    float* pv   = (float*)alloc((size_t)BB * CC * 4);
    float* invn = (float*)alloc((size_t)ROWS * 4);

    // bf16 weight offsets (elements)
    unsigned short* Wi_init = Wbf + 0;
    unsigned short* Wi_ploc = Wbf + 1081344;
    unsigned short* Wi_pctx = Wbf + 1343488;
    unsigned short* Wi_q    = Wbf + 1605632;
    unsigned short* Wi_k    = Wbf + 2392064;
    unsigned short* Wi_v    = Wbf + 3178496;
    unsigned short* Wi_mem  = Wbf + 3964928;
    unsigned short* Wi_comb = Wbf + 4489216;

    auto cvt = [&](const float* src, unsigned short* dst, size_t n) {
        int n4 = (int)(n / 4);
        cvt_kernel<<<dim3((n4 + 255) / 256), dim3(256), 0, stream>>>(src, dst, n4);
    };

    // ---- stem ----
    rownorm_kernel<<<dim3(ROWS), dim3(256), 0, stream>>>(images, invn);
    // zero Vt (pad cols k in [100,128) must be exact 0 for the PV MFMA)
    zero16_kernel<<<dim3(((int)((size_t)BB * CC * VTK * 2 / 16) + 255) / 256), dim3(256), 0, stream>>>(
        (uint4*)Vt, (int)((size_t)BB * CC * VTK * 2 / 16));
    cvt(W_initKB, Wi_init, (size_t)CC * DFEAT);
    cvt(W_ploc,  Wi_ploc, (size_t)CC * CC);
    cvt(W_pctx,  Wi_pctx, (size_t)CC * CC);
    cvt(W_q,     Wi_q,    (size_t)CC * 3 * CC);
    cvt(W_k,     Wi_k,    (size_t)CC * 3 * CC);
    cvt(W_v,     Wi_v,    (size_t)CC * 3 * CC);
    cvt(W_mem,   Wi_mem,  (size_t)CC * 2 * CC);
    cvt(W_comb,  Wi_comb, (size_t)CC * 2 * CC);

    dim3 gBig(ROWS / 128, 4), blk(256);
    // x_loc = norm(images) @ W_initKB.T + b  -> XJ0 col 0 and XJ1 col 0 (bf16)
    gemm_mfma<0, true, false, true, false><<<gBig, blk, 0, stream>>>(
        images, DFEAT, Wi_init, DFEAT, b_initKB, XJ0, XJLD, XJ1, DFEAT, invn, nullptr);
    bcast_kernel<<<dim3((ROWS * CC + 255) / 256), dim3(256), 0, stream>>>(initMem, XJ0);
    gemm_small<4><<<dim3(BB / 64, 8), blk, 0, stream>>>(q_enc, W_qIn, b_qIn, qcb);

    for (int t = 0; t < TT; ++t) {
        unsigned short* R  = (t & 1) ? XJ1 : XJ0;   // read buffer
        unsigned short* Wr = (t & 1) ? XJ0 : XJ1;   // write buffer (next x_ctx)
        // textual command
        gemm_small<0><<<dim3(BB / 64, 8), blk, 0, stream>>>(
            qcb, W_qIn2 + (size_t)t * CC * CC, b_qIn2 + (size_t)t * CC, qcmd);
        cmd_kernel<<<dim3(BB), blk, 0, stream>>>(qcmd, lstm, W_logit, b_logit, q_length, cmd);
        gemm_small<0><<<dim3(BB / 64, 8), blk, 0, stream>>>(cmd, W_pk, b_pk, pk);
        gemm_small<0><<<dim3(BB / 64, 8), blk, 0, stream>>>(cmd, W_pv, b_pv, pv);
        // prod = (x_loc@Wploc+b) * (xc@Wpctx+b)  -> R col 1024
        gemm_mfma<0, false, false, false, false><<<gBig, blk, 0, stream>>>(
            R, XJLD, Wi_ploc, CC, b_ploc, R + 2 * CC, XJLD, nullptr, CC, nullptr, nullptr);
        gemm_mfma<2, false, false, false, false><<<gBig, blk, 0, stream>>>(
            R + CC, XJLD, Wi_pctx, CC, b_pctx, R + 2 * CC, XJLD, nullptr, CC, nullptr, nullptr);
        // Q/K/V over x_joint (K=1536)
        gemm_mfma<0, false, false, false, false><<<gBig, blk, 0, stream>>>(
            R, XJLD, Wi_q, 3 * CC, b_q, Qb, CC, nullptr, 3 * CC, nullptr, nullptr);
        gemm_mfma<3, false, false, false, false><<<gBig, blk, 0, stream>>>(
            R, XJLD, Wi_k, 3 * CC, b_k, Kb, CC, nullptr, 3 * CC, nullptr, pk);
        gemm_mfma<3, false, false, false, true><<<gBig, blk, 0, stream>>>(
            R, XJLD, Wi_v, 3 * CC, b_v, Vt, CC, nullptr, 3 * CC, nullptr, pv);
        // attention -> message into R col 1024 (prod dead now)
        attn_mfma_kernel<<<dim3(BB, 2), blk, 0, stream>>>(Qb, Kb, Vt, entity_num, R + 2 * CC);
        // x_ctx_new = [xc | message] @ W_mem.T + b  -> Wr col 512
        gemm_mfma<0, false, false, false, false><<<gBig, blk, 0, stream>>>(
            R + CC, XJLD, Wi_mem, 2 * CC, b_mem, Wr + CC, XJLD, nullptr, 2 * CC, nullptr, nullptr);
    }
    // output = [x_loc | x_ctx] @ W_comb.T + b  (x_ctx final is in XJ0 col 512)
    gemm_mfma<0, false, true, false, false><<<gBig, blk, 0, stream>>>(
        XJ0, XJLD, Wi_comb, 2 * CC, b_comb, (float*)d_out, CC, nullptr, 2 * CC, nullptr, nullptr);
}

// Round 7
// 1575.007 us; speedup vs baseline: 5.0027x; 1.0845x over previous
//
#include <hip/hip_runtime.h>
#include <math.h>

#define BB 128
#define NN 100
#define LL 30
#define CC 512
#define DFEAT 2112
#define TT 4
#define ROWS (BB * NN)          // 12800
#define XJLD 1536               // x_joint row stride (bf16): [x_loc | x_ctx | prod]
#define INV_SQRT_C_F 0.04419417382415922f
#define QH 50                    // q-rows per attention block (2 halves)
#define VTK 128                  // Vt padded K (attention positions)

typedef __attribute__((ext_vector_type(8))) short short8;
typedef __attribute__((ext_vector_type(4))) float f32x4;

__device__ inline unsigned short f2bf(float f) {
    unsigned u = __float_as_uint(f);
    u += 0x7fff + ((u >> 16) & 1);          // round-to-nearest-even
    return (unsigned short)(u >> 16);
}
__device__ inline float b2f(unsigned short h) { return __uint_as_float((unsigned)h << 16); }

__device__ inline void async_ld16(const unsigned short* g, unsigned short* l) {
    __builtin_amdgcn_global_load_lds((const __attribute__((address_space(1))) void*)g,
                                     (__attribute__((address_space(3))) void*)l, 16, 0, 0);
}

// ---------------------------------------------------------------------------
// inv_norm[r] = 1 / max(||images[r,:]||, 1e-12)
// ---------------------------------------------------------------------------
__global__ __launch_bounds__(256) void rownorm_kernel(const float* __restrict__ img,
                                                      float* __restrict__ inv_norm) {
    int r = blockIdx.x;
    const float* p = img + (size_t)r * DFEAT;
    float s = 0.f;
    for (int i = threadIdx.x; i < DFEAT; i += 256) { float v = p[i]; s += v * v; }
    __shared__ float red[4];
    int lane = threadIdx.x & 63, wid = threadIdx.x >> 6;
#pragma unroll
    for (int off = 32; off > 0; off >>= 1) s += __shfl_down(s, off);
    if (lane == 0) red[wid] = s;
    __syncthreads();
    if (threadIdx.x == 0) {
        float tot = red[0] + red[1] + red[2] + red[3];
        inv_norm[r] = 1.f / fmaxf(sqrtf(tot), 1e-12f);
    }
}

// ---------------------------------------------------------------------------
// fp32 -> bf16 weight conversion (vectorized, n4 = n/4)
// ---------------------------------------------------------------------------
__global__ __launch_bounds__(256) void cvt_kernel(const float* __restrict__ s,
                                                  unsigned short* __restrict__ d, int n4) {
    int i = blockIdx.x * blockDim.x + threadIdx.x;
    if (i < n4) {
        float4 v = ((const float4*)s)[i];
        ushort4 o;
        o.x = f2bf(v.x); o.y = f2bf(v.y); o.z = f2bf(v.z); o.w = f2bf(v.w);
        ((ushort4*)d)[i] = o;
    }
}

__global__ void zero16_kernel(uint4* __restrict__ p, int n) {
    int i = blockIdx.x * blockDim.x + threadIdx.x;
    if (i < n) p[i] = uint4{0u, 0u, 0u, 0u};
}

// ---------------------------------------------------------------------------
// broadcast initMem[512] (fp32) into XJ0 x_ctx column (bf16, stride XJLD)
// ---------------------------------------------------------------------------
__global__ void bcast_kernel(const float* __restrict__ m, unsigned short* __restrict__ x) {
    int i = blockIdx.x * blockDim.x + threadIdx.x;
    if (i < ROWS * CC) {
        int r = i >> 9, c = i & (CC - 1);
        x[(size_t)r * XJLD + CC + c] = f2bf(m[c]);
    }
}

// ---------------------------------------------------------------------------
// MFMA GEMM: C[m,n] = epi( sum_k A[m,k] * W[n,k] )  -- W row-major [512][ldw] bf16
// tile 128x128, BK=64, 4 waves each owning a 64x64 quadrant (4x4 frags of
// 16x16x32 bf16 MFMA).
// LDS: [128 rows][8 chunks of 16B]; XOR-swizzle chunk ^= (row&7) applied on
// the GLOBAL source (LDS dest linear, global_load_lds constraint, m173) and
// identically on the read side -> 2-way banks (free) instead of 8-way.
// Grid: flat 1-D nwg = (M/128)*4; bijective XCD swizzle (m204) then
// wgid -> (mtile = wgid>>2, ntile = wgid&3): the 4 N-blocks of one M-tile are
// consecutive within an XCD chunk -> A-panel L2 reuse.
// MODE 0: v = acc + bias[n]
// MODE 2: v = (acc + bias[n]) * C_prev   (proj_loc * proj_ctx, in-place on C)
// MODE 3: v = (acc + bias[n]) * rowscale[(r/100)*512 + n]
// AF32: A fp32 (stem), reg-staged+converted with optional row scale arsc.
// OUTF32: write fp32 (d_out).  DUAL: also write C2 (stem).
// VT: write transposed per-batch layout Vt[b][n][VTK] (attention V operand).
// ---------------------------------------------------------------------------
template <int MODE, bool AF32, bool OUTF32, bool DUAL, bool VT>
__global__ __launch_bounds__(256) void gemm_mfma(
    const void* __restrict__ A_, int lda,
    const unsigned short* __restrict__ W, int ldw,
    const float* __restrict__ bias,
    void* __restrict__ C_, int ldc,
    void* __restrict__ C2_,
    int K,
    const float* __restrict__ arsc,
    const float* __restrict__ rowscale) {
    __shared__ unsigned short As[128 * 64];
    __shared__ unsigned short Bs[128 * 64];
    const int t = threadIdx.x;
    const int l = t & 63;
    const int wv = t >> 6;
    const int wr = wv >> 1, wc = wv & 1;
    const int lg = l >> 4, lm = l & 15;
    // bijective XCD swizzle (m204) + panel-major decode
    const int nwg = gridDim.x;
    const int qq = nwg >> 3, rr = nwg & 7;
    const int xcd = blockIdx.x & 7, idx = blockIdx.x >> 3;
    const int wgid = (xcd < rr ? xcd * (qq + 1) : rr * (qq + 1) + (xcd - rr) * qq) + idx;
    const int m0 = (wgid >> 2) * 128, n0 = (wgid & 3) * 128;

    f32x4 acc[4][4];
#pragma unroll
    for (int mi = 0; mi < 4; ++mi)
#pragma unroll
        for (int ni = 0; ni < 4; ++ni) acc[mi][ni] = {0.f, 0.f, 0.f, 0.f};

    for (int k0 = 0; k0 < K; k0 += 64) {
        if (AF32) {
            // reg-stage fp32 A -> bf16 LDS, swizzled ds_write (2 thr/row, 32 cols each)
            const float* Af = (const float*)A_;
            int row = t >> 1, half = t & 1;
            const float* s = Af + (size_t)(m0 + row) * lda + k0 + half * 32;
            float sc = arsc ? arsc[m0 + row] : 1.f;
#pragma unroll
            for (int c = 0; c < 4; ++c) {
                float4 v0 = *(const float4*)(s + c * 8);
                float4 v1 = *(const float4*)(s + c * 8 + 4);
                short8 h;
                h[0] = (short)f2bf(v0.x * sc); h[1] = (short)f2bf(v0.y * sc);
                h[2] = (short)f2bf(v0.z * sc); h[3] = (short)f2bf(v0.w * sc);
                h[4] = (short)f2bf(v1.x * sc); h[5] = (short)f2bf(v1.y * sc);
                h[6] = (short)f2bf(v1.z * sc); h[7] = (short)f2bf(v1.w * sc);
                int cs = half * 4 + c;
                *(short8*)&As[row * 64 + ((cs ^ (row & 7)) * 8)] = h;
            }
        } else {
            const unsigned short* Ah = (const unsigned short*)A_;
#pragma unroll
            for (int i = 0; i < 4; ++i) {
                int lin = t + i * 256;           // 16B chunk id; LDS dest linear
                int row = lin >> 3, seg = lin & 7;
                async_ld16(Ah + (size_t)(m0 + row) * lda + k0 + ((seg ^ (row & 7)) * 8),
                           &As[lin * 8]);
            }
        }
#pragma unroll
        for (int i = 0; i < 4; ++i) {
            int lin = t + i * 256;
            int row = lin >> 3, seg = lin & 7;
            async_ld16(W + (size_t)(n0 + row) * ldw + k0 + ((seg ^ (row & 7)) * 8),
                       &Bs[lin * 8]);
        }
        __syncthreads();

#pragma unroll
        for (int kk = 0; kk < 2; ++kk) {
            short8 af[4], bq[4];
#pragma unroll
            for (int mi = 0; mi < 4; ++mi) {
                int row = wr * 64 + mi * 16 + lm;
                int cs = kk * 4 + lg;
                af[mi] = *(const short8*)&As[row * 64 + ((cs ^ (row & 7)) * 8)];
            }
#pragma unroll
            for (int ni = 0; ni < 4; ++ni) {
                int row = wc * 64 + ni * 16 + lm;
                int cs = kk * 4 + lg;
                bq[ni] = *(const short8*)&Bs[row * 64 + ((cs ^ (row & 7)) * 8)];
            }
#pragma unroll
            for (int mi = 0; mi < 4; ++mi)
#pragma unroll
                for (int ni = 0; ni < 4; ++ni)
                    acc[mi][ni] = __builtin_amdgcn_mfma_f32_16x16x32_bf16(af[mi], bq[ni], acc[mi][ni], 0, 0, 0);
        }
        __syncthreads();
    }

    // epilogue: C/D frag layout (m89): col = lane&15, row = (lane>>4)*4 + reg
#pragma unroll
    for (int mi = 0; mi < 4; ++mi) {
        int rbase = m0 + wr * 64 + mi * 16 + lg * 4;
#pragma unroll
        for (int ni = 0; ni < 4; ++ni) {
            int n = n0 + wc * 64 + ni * 16 + lm;
            float bv = bias[n];
#pragma unroll
            for (int j = 0; j < 4; ++j) {
                int r = rbase + j;
                float v = acc[mi][ni][j] + bv;
                size_t off = (size_t)r * ldc + n;
                if (MODE == 2) v *= b2f(((const unsigned short*)C_)[off]);
                if (MODE == 3) v *= rowscale[(size_t)(r / NN) * CC + n];
                if (OUTF32) {
                    ((float*)C_)[off] = v;
                } else {
                    unsigned short hv = f2bf(v);
                    if (VT) {
                        int b2 = r / NN, rl = r - b2 * NN;
                        ((unsigned short*)C_)[((size_t)b2 * CC + n) * VTK + rl] = hv;
                    } else {
                        ((unsigned short*)C_)[off] = hv;
                        if (DUAL) ((unsigned short*)C2_)[off] = hv;
                    }
                }
            }
        }
    }
}

// ---------------------------------------------------------------------------
// small fp32 GEMM for M=128 rows: C[m,n] = epi(sum_k A[m,k]*W[n,k] + bias[n])
// 64x64 tile, BK=32, 256 thr, 4x4 micro. grid (M/64, 8).
// MODE 0: bias; MODE 4: elu(bias)
// ---------------------------------------------------------------------------
template <int MODE>
__global__ __launch_bounds__(256) void gemm_small(
    const float* __restrict__ A, const float* __restrict__ W,
    const float* __restrict__ bias, float* __restrict__ C) {
    __shared__ float As[32 * 72];
    __shared__ float Bs[32 * 72];
    const int t = threadIdx.x;
    const int m0 = blockIdx.x * 64, n0 = blockIdx.y * 64;
    const int tr = t >> 4, tc = t & 15;
    float acc[4][4];
#pragma unroll
    for (int i = 0; i < 4; ++i)
#pragma unroll
        for (int j = 0; j < 4; ++j) acc[i][j] = 0.f;

    for (int k0 = 0; k0 < CC; k0 += 32) {
        int row = t >> 2, seg = t & 3;
        {
            const float* s = A + (size_t)(m0 + row) * CC + k0 + seg * 8;
            float4 v0 = *(const float4*)s, v1 = *(const float4*)(s + 4);
            As[(seg * 8 + 0) * 72 + row] = v0.x; As[(seg * 8 + 1) * 72 + row] = v0.y;
            As[(seg * 8 + 2) * 72 + row] = v0.z; As[(seg * 8 + 3) * 72 + row] = v0.w;
            As[(seg * 8 + 4) * 72 + row] = v1.x; As[(seg * 8 + 5) * 72 + row] = v1.y;
            As[(seg * 8 + 6) * 72 + row] = v1.z; As[(seg * 8 + 7) * 72 + row] = v1.w;
        }
        {
            const float* s = W + (size_t)(n0 + row) * CC + k0 + seg * 8;
            float4 v0 = *(const float4*)s, v1 = *(const float4*)(s + 4);
            Bs[(seg * 8 + 0) * 72 + row] = v0.x; Bs[(seg * 8 + 1) * 72 + row] = v0.y;
            Bs[(seg * 8 + 2) * 72 + row] = v0.z; Bs[(seg * 8 + 3) * 72 + row] = v0.w;
            Bs[(seg * 8 + 4) * 72 + row] = v1.x; Bs[(seg * 8 + 5) * 72 + row] = v1.y;
            Bs[(seg * 8 + 6) * 72 + row] = v1.z; Bs[(seg * 8 + 7) * 72 + row] = v1.w;
        }
        __syncthreads();
#pragma unroll
        for (int kk = 0; kk < 32; ++kk) {
            float4 a = *(const float4*)&As[kk * 72 + tr * 4];
            float4 b = *(const float4*)&Bs[kk * 72 + tc * 4];
            float av[4] = {a.x, a.y, a.z, a.w}, bv[4] = {b.x, b.y, b.z, b.w};
#pragma unroll
            for (int i = 0; i < 4; ++i)
#pragma unroll
                for (int j = 0; j < 4; ++j) acc[i][j] = fmaf(av[i], bv[j], acc[i][j]);
        }
        __syncthreads();
    }
#pragma unroll
    for (int i = 0; i < 4; ++i) {
#pragma unroll
        for (int j = 0; j < 4; ++j) {
            int n = n0 + tc * 4 + j;
            float v = acc[i][j] + bias[n];
            if (MODE == 4) v = v > 0.f ? v : expm1f(v);
            C[(size_t)(m0 + tr * 4 + i) * CC + n] = v;
        }
    }
}

// ---------------------------------------------------------------------------
// Per-batch command extraction (fp32)
// ---------------------------------------------------------------------------
__global__ __launch_bounds__(256) void cmd_kernel(
    const float* __restrict__ qcmd, const float* __restrict__ lstm,
    const float* __restrict__ wlogit, const float* __restrict__ blogit,
    const int* __restrict__ qlen, float* __restrict__ cmd) {
    const int b = blockIdx.x;
    const int t = threadIdx.x;
    __shared__ float qw[CC];
    __shared__ float att[LL];
    for (int c = t; c < CC; c += 256) qw[c] = qcmd[b * CC + c] * wlogit[c];
    __syncthreads();
    const int wid = t >> 6, lane = t & 63;
    for (int l = wid; l < LL; l += 4) {
        const float* lp = lstm + ((size_t)b * LL + l) * CC;
        float s = 0.f;
        for (int c = lane; c < CC; c += 64) s = fmaf(qw[c], lp[c], s);
#pragma unroll
        for (int off = 32; off > 0; off >>= 1) s += __shfl_down(s, off);
        if (lane == 0) att[l] = s + blogit[0];
    }
    __syncthreads();
    if (t == 0) {
        int Lq = qlen[b];
        float mx = -1e30f;
        for (int l = 0; l < LL; ++l) {
            if (l >= Lq) att[l] = -1e30f;
            mx = fmaxf(mx, att[l]);
        }
        float sum = 0.f;
        for (int l = 0; l < LL; ++l) { float e = expf(att[l] - mx); att[l] = e; sum += e; }
        float inv = 1.f / sum;
        for (int l = 0; l < LL; ++l) att[l] *= inv;
    }
    __syncthreads();
    for (int c = t; c < CC; c += 256) {
        float s = 0.f;
        for (int l = 0; l < LL; ++l) s = fmaf(att[l], lstm[((size_t)b * LL + l) * CC + c], s);
        cmd[b * CC + c] = s;
    }
}

// ---------------------------------------------------------------------------
// MFMA fused attention: per (b, q-half).  Qs/Ks staging XOR-swizzled
// (chunk ^= row&7 on global src, linear LDS dest; same XOR on reads).
// ---------------------------------------------------------------------------
__global__ __launch_bounds__(256) void attn_mfma_kernel(
    const unsigned short* __restrict__ Qm, const unsigned short* __restrict__ Km,
    const unsigned short* __restrict__ Vt, const int* __restrict__ entnum,
    unsigned short* __restrict__ msg) {
    __shared__ char ldsraw[64 * 132 * 4];      // 33792 B
    float* S = (float*)ldsraw;                 // [64][132] fp32 (phase B/C)
    unsigned short* Qs = (unsigned short*)ldsraw;            // [64][64] bf16 (phase A)
    unsigned short* Ks = (unsigned short*)(ldsraw + 8192);   // [112][64] bf16 (phase A)
    const int b = blockIdx.x;
    const int qbase = blockIdx.y * QH;
    const int t = threadIdx.x;
    const int wv = t >> 6, l = t & 63, lg = l >> 4, lm = l & 15;
    const unsigned short* Qp = Qm + ((size_t)b * NN + qbase) * CC;
    const unsigned short* Kp = Km + (size_t)b * NN * CC;

    // ---- phase A: scores (each wave owns 16 M-rows x 112 cols) ----
    f32x4 sacc[7];
#pragma unroll
    for (int i = 0; i < 7; ++i) sacc[i] = {0.f, 0.f, 0.f, 0.f};

    for (int k0 = 0; k0 < CC; k0 += 64) {
#pragma unroll
        for (int i = 0; i < 2; ++i) {          // Qs: 512 chunks
            int lin = t + i * 256;
            int row = lin >> 3, seg = lin & 7;
            async_ld16(Qp + (size_t)row * CC + k0 + ((seg ^ (row & 7)) * 8), &Qs[lin * 8]);
        }
#pragma unroll
        for (int i = 0; i < 4; ++i) {          // Ks: 896 chunks (wave-uniform tail)
            int lin = t + i * 256;
            if (lin < 896) {
                int row = lin >> 3, seg = lin & 7;
                async_ld16(Kp + (size_t)row * CC + k0 + ((seg ^ (row & 7)) * 8), &Ks[lin * 8]);
            }
        }
        __syncthreads();
#pragma unroll
        for (int kk = 0; kk < 2; ++kk) {
            int arow = wv * 16 + lm;
            int cs = kk * 4 + lg;
            short8 a = *(const short8*)&Qs[arow * 64 + ((cs ^ (arow & 7)) * 8)];
#pragma unroll
            for (int nf = 0; nf < 7; ++nf) {
                int brow = nf * 16 + lm;
                short8 bb = *(const short8*)&Ks[brow * 64 + ((cs ^ (brow & 7)) * 8)];
                sacc[nf] = __builtin_amdgcn_mfma_f32_16x16x32_bf16(a, bb, sacc[nf], 0, 0, 0);
            }
        }
        __syncthreads();
    }
#pragma unroll
    for (int nf = 0; nf < 7; ++nf)
#pragma unroll
        for (int j = 0; j < 4; ++j)
            S[(wv * 16 + lg * 4 + j) * 132 + nf * 16 + lm] = sacc[nf][j] * INV_SQRT_C_F;
    __syncthreads();

    // ---- phase B: masked softmax (rows 0..49); zero cols [en,128) ----
    const int en = entnum[b];
    for (int q = wv; q < QH; q += 4) {
        float v0 = (l < en) ? S[q * 132 + l] : -1e30f;
        int k1 = l + 64;
        float v1 = (k1 < en) ? S[q * 132 + k1] : -1e30f;
        float mx = fmaxf(v0, v1);
#pragma unroll
        for (int o = 32; o > 0; o >>= 1) mx = fmaxf(mx, __shfl_xor(mx, o));
        float e0 = (l < en) ? expf(v0 - mx) : 0.f;
        float e1 = (k1 < en) ? expf(v1 - mx) : 0.f;
        float ss = e0 + e1;
#pragma unroll
        for (int o = 32; o > 0; o >>= 1) ss += __shfl_xor(ss, o);
        float inv = 1.f / ss;
        S[q * 132 + l] = e0 * inv;
        S[q * 132 + k1] = e1 * inv;
    }
    __syncthreads();

    // ---- phase C: msg = P V (waves split N: wave wv owns cols wv*128..+127) ----
    f32x4 acc[4][8];
#pragma unroll
    for (int mf = 0; mf < 4; ++mf)
#pragma unroll
        for (int nf = 0; nf < 8; ++nf) acc[mf][nf] = {0.f, 0.f, 0.f, 0.f};

    const unsigned short* Vb = Vt + (size_t)b * CC * VTK;
    for (int ks = 0; ks < 4; ++ks) {
        int k0 = ks * 32;
        short8 pa[4];
#pragma unroll
        for (int mf = 0; mf < 4; ++mf) {
            const float* sp = &S[(mf * 16 + lm) * 132 + k0 + lg * 8];
            short8 h;
#pragma unroll
            for (int jj = 0; jj < 8; ++jj) h[jj] = (short)f2bf(sp[jj]);
            pa[mf] = h;
        }
#pragma unroll
        for (int nf = 0; nf < 8; ++nf) {
            short8 bb = *(const short8*)(Vb + ((size_t)(wv * 128 + nf * 16 + lm)) * VTK + k0 + lg * 8);
#pragma unroll
            for (int mf = 0; mf < 4; ++mf)
                acc[mf][nf] = __builtin_amdgcn_mfma_f32_16x16x32_bf16(pa[mf], bb, acc[mf][nf], 0, 0, 0);
        }
    }
    // epilogue: rows q < 50 only
#pragma unroll
    for (int mf = 0; mf < 4; ++mf) {
#pragma unroll
        for (int j = 0; j < 4; ++j) {
            int q = mf * 16 + lg * 4 + j;
            if (q < QH) {
                size_t rb = ((size_t)b * NN + qbase + q) * XJLD;
#pragma unroll
                for (int nf = 0; nf < 8; ++nf)
                    msg[rb + wv * 128 + nf * 16 + lm] = f2bf(acc[mf][nf][j]);
            }
        }
    }
}

// ---------------------------------------------------------------------------
extern "C" void kernel_launch(void* const* d_in, const int* in_sizes, int n_in,
                              void* d_out, int out_size, void* d_ws, size_t ws_size,
                              hipStream_t stream) {
    const float* images   = (const float*)d_in[0];
    const float* q_enc    = (const float*)d_in[1];
    const float* lstm     = (const float*)d_in[2];
    const float* W_initKB = (const float*)d_in[3];
    const float* b_initKB = (const float*)d_in[4];
    const float* initMem  = (const float*)d_in[5];
    const float* W_qIn    = (const float*)d_in[6];
    const float* b_qIn    = (const float*)d_in[7];
    const float* W_qIn2   = (const float*)d_in[8];
    const float* b_qIn2   = (const float*)d_in[9];
    const float* W_logit  = (const float*)d_in[10];
    const float* b_logit  = (const float*)d_in[11];
    const float* W_ploc   = (const float*)d_in[12];
    const float* b_ploc   = (const float*)d_in[13];
    const float* W_pctx   = (const float*)d_in[14];
    const float* b_pctx   = (const float*)d_in[15];
    const float* W_q      = (const float*)d_in[16];
    const float* b_q      = (const float*)d_in[17];
    const float* W_k      = (const float*)d_in[18];
    const float* b_k      = (const float*)d_in[19];
    const float* W_v      = (const float*)d_in[20];
    const float* b_v      = (const float*)d_in[21];
    const float* W_pk     = (const float*)d_in[22];
    const float* b_pk     = (const float*)d_in[23];
    const float* W_pv     = (const float*)d_in[24];
    const float* b_pv     = (const float*)d_in[25];
    const float* W_mem    = (const float*)d_in[26];
    const float* b_mem    = (const float*)d_in[27];
    const float* W_comb   = (const float*)d_in[28];
    const float* b_comb   = (const float*)d_in[29];
    const int* q_length   = (const int*)d_in[30];
    const int* entity_num = (const int*)d_in[31];
    (void)in_sizes; (void)n_in; (void)out_size; (void)ws_size;

    // ---- workspace carve ----
    char* p = (char*)d_ws;
    auto alloc = [&](size_t bytes) { char* q = p; p += (bytes + 255) & ~(size_t)255; return q; };
    unsigned short* XJ0 = (unsigned short*)alloc((size_t)ROWS * XJLD * 2);
    unsigned short* XJ1 = (unsigned short*)alloc((size_t)ROWS * XJLD * 2);
    unsigned short* Qb  = (unsigned short*)alloc((size_t)ROWS * CC * 2);
    unsigned short* Kb  = (unsigned short*)alloc((size_t)ROWS * CC * 2);
    unsigned short* Vt  = (unsigned short*)alloc((size_t)BB * CC * VTK * 2);
    unsigned short* Wbf = (unsigned short*)alloc((size_t)5013504 * 2);
    float* qcb  = (float*)alloc((size_t)BB * CC * 4);
    float* qcmd = (float*)alloc((size_t)BB * CC * 4);
    float* cmd  = (float*)alloc((size_t)BB * CC * 4);
    float* pk   = (float*)alloc((size_t)BB * CC * 4);
    float* pv   = (float*)alloc((size_t)BB * CC * 4);
    float* invn = (float*)alloc((size_t)ROWS * 4);

    // bf16 weight offsets (elements)
    unsigned short* Wi_init = Wbf + 0;
    unsigned short* Wi_ploc = Wbf + 1081344;
    unsigned short* Wi_pctx = Wbf + 1343488;
    unsigned short* Wi_q    = Wbf + 1605632;
    unsigned short* Wi_k    = Wbf + 2392064;
    unsigned short* Wi_v    = Wbf + 3178496;
    unsigned short* Wi_mem  = Wbf + 3964928;
    unsigned short* Wi_comb = Wbf + 4489216;

    auto cvt = [&](const float* src, unsigned short* dst, size_t n) {
        int n4 = (int)(n / 4);
        cvt_kernel<<<dim3((n4 + 255) / 256), dim3(256), 0, stream>>>(src, dst, n4);
    };

    // ---- stem ----
    rownorm_kernel<<<dim3(ROWS), dim3(256), 0, stream>>>(images, invn);
    // zero Vt (pad cols k in [100,128) must be exact 0 for the PV MFMA)
    zero16_kernel<<<dim3(((int)((size_t)BB * CC * VTK * 2 / 16) + 255) / 256), dim3(256), 0, stream>>>(
        (uint4*)Vt, (int)((size_t)BB * CC * VTK * 2 / 16));
    cvt(W_initKB, Wi_init, (size_t)CC * DFEAT);
    cvt(W_ploc,  Wi_ploc, (size_t)CC * CC);
    cvt(W_pctx,  Wi_pctx, (size_t)CC * CC);
    cvt(W_q,     Wi_q,    (size_t)CC * 3 * CC);
    cvt(W_k,     Wi_k,    (size_t)CC * 3 * CC);
    cvt(W_v,     Wi_v,    (size_t)CC * 3 * CC);
    cvt(W_mem,   Wi_mem,  (size_t)CC * 2 * CC);
    cvt(W_comb,  Wi_comb, (size_t)CC * 2 * CC);

    dim3 gBig((ROWS / 128) * 4), blk(256);
    // x_loc = norm(images) @ W_initKB.T + b  -> XJ0 col 0 and XJ1 col 0 (bf16)
    gemm_mfma<0, true, false, true, false><<<gBig, blk, 0, stream>>>(
        images, DFEAT, Wi_init, DFEAT, b_initKB, XJ0, XJLD, XJ1, DFEAT, invn, nullptr);
    bcast_kernel<<<dim3((ROWS * CC + 255) / 256), dim3(256), 0, stream>>>(initMem, XJ0);
    gemm_small<4><<<dim3(BB / 64, 8), blk, 0, stream>>>(q_enc, W_qIn, b_qIn, qcb);

    for (int t = 0; t < TT; ++t) {
        unsigned short* R  = (t & 1) ? XJ1 : XJ0;   // read buffer
        unsigned short* Wr = (t & 1) ? XJ0 : XJ1;   // write buffer (next x_ctx)
        // textual command
        gemm_small<0><<<dim3(BB / 64, 8), blk, 0, stream>>>(
            qcb, W_qIn2 + (size_t)t * CC * CC, b_qIn2 + (size_t)t * CC, qcmd);
        cmd_kernel<<<dim3(BB), blk, 0, stream>>>(qcmd, lstm, W_logit, b_logit, q_length, cmd);
        gemm_small<0><<<dim3(BB / 64, 8), blk, 0, stream>>>(cmd, W_pk, b_pk, pk);
        gemm_small<0><<<dim3(BB / 64, 8), blk, 0, stream>>>(cmd, W_pv, b_pv, pv);
        // prod = (x_loc@Wploc+b) * (xc@Wpctx+b)  -> R col 1024
        gemm_mfma<0, false, false, false, false><<<gBig, blk, 0, stream>>>(
            R, XJLD, Wi_ploc, CC, b_ploc, R + 2 * CC, XJLD, nullptr, CC, nullptr, nullptr);
        gemm_mfma<2, false, false, false, false><<<gBig, blk, 0, stream>>>(
            R + CC, XJLD, Wi_pctx, CC, b_pctx, R + 2 * CC, XJLD, nullptr, CC, nullptr, nullptr);
        // Q/K/V over x_joint (K=1536)
        gemm_mfma<0, false, false, false, false><<<gBig, blk, 0, stream>>>(
            R, XJLD, Wi_q, 3 * CC, b_q, Qb, CC, nullptr, 3 * CC, nullptr, nullptr);
        gemm_mfma<3, false, false, false, false><<<gBig, blk, 0, stream>>>(
            R, XJLD, Wi_k, 3 * CC, b_k, Kb, CC, nullptr, 3 * CC, nullptr, pk);
        gemm_mfma<3, false, false, false, true><<<gBig, blk, 0, stream>>>(
            R, XJLD, Wi_v, 3 * CC, b_v, Vt, CC, nullptr, 3 * CC, nullptr, pv);
        // attention -> message into R col 1024 (prod dead now)
        attn_mfma_kernel<<<dim3(BB, 2), blk, 0, stream>>>(Qb, Kb, Vt, entity_num, R + 2 * CC);
        // x_ctx_new = [xc | message] @ W_mem.T + b  -> Wr col 512
        gemm_mfma<0, false, false, false, false><<<gBig, blk, 0, stream>>>(
            R + CC, XJLD, Wi_mem, 2 * CC, b_mem, Wr + CC, XJLD, nullptr, 2 * CC, nullptr, nullptr);
    }
    // output = [x_loc | x_ctx] @ W_comb.T + b  (x_ctx final is in XJ0 col 512)
    gemm_mfma<0, false, true, false, false><<<gBig, blk, 0, stream>>>(
        XJ0, XJLD, Wi_comb, 2 * CC, b_comb, (float*)d_out, CC, nullptr, 2 * CC, nullptr, nullptr);
}

// Round 8
// 1568.790 us; speedup vs baseline: 5.0226x; 1.0040x over previous
//
#include <hip/hip_runtime.h>
#include <math.h>

#define BB 128
#define NN 100
#define LL 30
#define CC 512
#define DFEAT 2112
#define TT 4
#define ROWS (BB * NN)          // 12800
#define XJLD 1536               // x_joint row stride (bf16): [x_loc | x_ctx | prod]
#define INV_SQRT_C_F 0.04419417382415922f
#define QH 50                    // q-rows per attention block (2 halves)
#define VTK 128                  // Vt padded K (attention positions)

typedef __attribute__((ext_vector_type(8))) short short8;
typedef __attribute__((ext_vector_type(4))) float f32x4;

__device__ inline unsigned short f2bf(float f) {
    unsigned u = __float_as_uint(f);
    u += 0x7fff + ((u >> 16) & 1);          // round-to-nearest-even
    return (unsigned short)(u >> 16);
}
__device__ inline float b2f(unsigned short h) { return __uint_as_float((unsigned)h << 16); }

__device__ inline void async_ld16(const unsigned short* g, unsigned short* l) {
    __builtin_amdgcn_global_load_lds((const __attribute__((address_space(1))) void*)g,
                                     (__attribute__((address_space(3))) void*)l, 16, 0, 0);
}

// bijective XCD swizzle (m204): blockIdx.x -> wgid
__device__ inline int xcd_swz(int bid, int nwg) {
    int qq = nwg >> 3, rr = nwg & 7;
    int xcd = bid & 7, idx = bid >> 3;
    return (xcd < rr ? xcd * (qq + 1) : rr * (qq + 1) + (xcd - rr) * qq) + idx;
}

// ---------------------------------------------------------------------------
__global__ __launch_bounds__(256) void rownorm_kernel(const float* __restrict__ img,
                                                      float* __restrict__ inv_norm) {
    int r = blockIdx.x;
    const float* p = img + (size_t)r * DFEAT;
    float s = 0.f;
    for (int i = threadIdx.x; i < DFEAT; i += 256) { float v = p[i]; s += v * v; }
    __shared__ float red[4];
    int lane = threadIdx.x & 63, wid = threadIdx.x >> 6;
#pragma unroll
    for (int off = 32; off > 0; off >>= 1) s += __shfl_down(s, off);
    if (lane == 0) red[wid] = s;
    __syncthreads();
    if (threadIdx.x == 0) {
        float tot = red[0] + red[1] + red[2] + red[3];
        inv_norm[r] = 1.f / fmaxf(sqrtf(tot), 1e-12f);
    }
}

__global__ __launch_bounds__(256) void cvt_kernel(const float* __restrict__ s,
                                                  unsigned short* __restrict__ d, int n4) {
    int i = blockIdx.x * blockDim.x + threadIdx.x;
    if (i < n4) {
        float4 v = ((const float4*)s)[i];
        ushort4 o;
        o.x = f2bf(v.x); o.y = f2bf(v.y); o.z = f2bf(v.z); o.w = f2bf(v.w);
        ((ushort4*)d)[i] = o;
    }
}

__global__ void zero16_kernel(uint4* __restrict__ p, int n) {
    int i = blockIdx.x * blockDim.x + threadIdx.x;
    if (i < n) p[i] = uint4{0u, 0u, 0u, 0u};
}

__global__ void bcast_kernel(const float* __restrict__ m, unsigned short* __restrict__ x) {
    int i = blockIdx.x * blockDim.x + threadIdx.x;
    if (i < ROWS * CC) {
        int r = i >> 9, c = i & (CC - 1);
        x[(size_t)r * XJLD + CC + c] = f2bf(m[c]);
    }
}

// ---------------------------------------------------------------------------
// Generic dbuf MFMA GEMM (bf16 A): C[m,n] = epi(sum_k A[m,k]*W[n,k])
// 128x128 tile, BK=64, 2-phase double-buffer (T3 minimum): STAGE(next) ->
// compute(cur) -> __syncthreads.  XOR swizzle chunk^=(row&7) on global src
// (LDS linear) + same XOR on reads -> conflict-free (verified R7: 0 conflicts).
// grid flat (M/128)*4, XCD-swizzled, panel-major (4 N-blocks consecutive).
// EPI 0: bf16 store acc+bias.  EPI 1: fp32 store acc+bias (d_out).
// ---------------------------------------------------------------------------
template <int EPI>
__global__ __launch_bounds__(256) void gemm_dbuf(
    const unsigned short* __restrict__ A, int lda,
    const unsigned short* __restrict__ W, int ldw,
    const float* __restrict__ bias,
    void* __restrict__ C_, int ldc, int K) {
    __shared__ unsigned short As[2][128 * 64];
    __shared__ unsigned short Bs[2][128 * 64];
    const int t = threadIdx.x;
    const int l = t & 63;
    const int wv = t >> 6;
    const int wr = wv >> 1, wc = wv & 1;
    const int lg = l >> 4, lm = l & 15;
    const int wgid = xcd_swz(blockIdx.x, gridDim.x);
    const int m0 = (wgid >> 2) * 128, n0 = (wgid & 3) * 128;

    f32x4 acc[4][4];
#pragma unroll
    for (int mi = 0; mi < 4; ++mi)
#pragma unroll
        for (int ni = 0; ni < 4; ++ni) acc[mi][ni] = {0.f, 0.f, 0.f, 0.f};

    auto stage = [&](int buf, int k0) {
#pragma unroll
        for (int i = 0; i < 4; ++i) {
            int lin = t + i * 256;
            int row = lin >> 3, seg = lin & 7;
            async_ld16(A + (size_t)(m0 + row) * lda + k0 + ((seg ^ (row & 7)) * 8),
                       &As[buf][lin * 8]);
            async_ld16(W + (size_t)(n0 + row) * ldw + k0 + ((seg ^ (row & 7)) * 8),
                       &Bs[buf][lin * 8]);
        }
    };

    const int nk = K >> 6;
    stage(0, 0);
    __syncthreads();
    for (int kt = 0; kt < nk; ++kt) {
        int cur = kt & 1;
        if (kt + 1 < nk) stage(cur ^ 1, (kt + 1) * 64);
#pragma unroll
        for (int kk = 0; kk < 2; ++kk) {
            short8 af[4], bq[4];
#pragma unroll
            for (int mi = 0; mi < 4; ++mi) {
                int row = wr * 64 + mi * 16 + lm;
                int cs = kk * 4 + lg;
                af[mi] = *(const short8*)&As[cur][row * 64 + ((cs ^ (row & 7)) * 8)];
            }
#pragma unroll
            for (int ni = 0; ni < 4; ++ni) {
                int row = wc * 64 + ni * 16 + lm;
                int cs = kk * 4 + lg;
                bq[ni] = *(const short8*)&Bs[cur][row * 64 + ((cs ^ (row & 7)) * 8)];
            }
#pragma unroll
            for (int mi = 0; mi < 4; ++mi)
#pragma unroll
                for (int ni = 0; ni < 4; ++ni)
                    acc[mi][ni] = __builtin_amdgcn_mfma_f32_16x16x32_bf16(af[mi], bq[ni], acc[mi][ni], 0, 0, 0);
        }
        __syncthreads();
    }

#pragma unroll
    for (int mi = 0; mi < 4; ++mi) {
        int rbase = m0 + wr * 64 + mi * 16 + lg * 4;
#pragma unroll
        for (int ni = 0; ni < 4; ++ni) {
            int n = n0 + wc * 64 + ni * 16 + lm;
            float bv = bias[n];
#pragma unroll
            for (int j = 0; j < 4; ++j) {
                int r = rbase + j;
                float v = acc[mi][ni][j] + bv;
                if (EPI == 1) ((float*)C_)[(size_t)r * ldc + n] = v;
                else ((unsigned short*)C_)[(size_t)r * ldc + n] = f2bf(v);
            }
        }
    }
}

// ---------------------------------------------------------------------------
// Fused QKV GEMM (dbuf, BK=64): A = x_joint [12800][1536].
// grid flat 1200: wgid -> mtile = wgid/12, sub = wgid%12; op = sub>>2
// (0=Q,1=K,2=V), n0 = (sub&3)*128.  12 consecutive sub-blocks share the
// A-panel (same XCD chunk -> L2 reuse).
// Q: Qb = acc+b_q.  K: Kb = (acc+b_k)*pk.  V: Vt[b][n][VTK] = (acc+b_v)*pv.
// ---------------------------------------------------------------------------
__global__ __launch_bounds__(256) void gemm_qkv(
    const unsigned short* __restrict__ A,
    const unsigned short* __restrict__ Wq, const unsigned short* __restrict__ Wk,
    const unsigned short* __restrict__ Wv,
    const float* __restrict__ bq_, const float* __restrict__ bk_,
    const float* __restrict__ bv_,
    unsigned short* __restrict__ Qb, unsigned short* __restrict__ Kb,
    unsigned short* __restrict__ Vt,
    const float* __restrict__ pk, const float* __restrict__ pv) {
    __shared__ unsigned short As[2][128 * 64];
    __shared__ unsigned short Bs[2][128 * 64];
    const int t = threadIdx.x;
    const int l = t & 63;
    const int wv_ = t >> 6;
    const int wr = wv_ >> 1, wc = wv_ & 1;
    const int lg = l >> 4, lm = l & 15;
    const int wgid = xcd_swz(blockIdx.x, gridDim.x);
    const int mtile = wgid / 12, sub = wgid - mtile * 12;
    const int op = sub >> 2;
    const int m0 = mtile * 128, n0 = (sub & 3) * 128;
    const unsigned short* W = (op == 0) ? Wq : (op == 1) ? Wk : Wv;
    const float* bias = (op == 0) ? bq_ : (op == 1) ? bk_ : bv_;

    f32x4 acc[4][4];
#pragma unroll
    for (int mi = 0; mi < 4; ++mi)
#pragma unroll
        for (int ni = 0; ni < 4; ++ni) acc[mi][ni] = {0.f, 0.f, 0.f, 0.f};

    auto stage = [&](int buf, int k0) {
#pragma unroll
        for (int i = 0; i < 4; ++i) {
            int lin = t + i * 256;
            int row = lin >> 3, seg = lin & 7;
            async_ld16(A + (size_t)(m0 + row) * XJLD + k0 + ((seg ^ (row & 7)) * 8),
                       &As[buf][lin * 8]);
            async_ld16(W + (size_t)(n0 + row) * XJLD + k0 + ((seg ^ (row & 7)) * 8),
                       &Bs[buf][lin * 8]);
        }
    };

    const int nk = XJLD >> 6;   // 24
    stage(0, 0);
    __syncthreads();
    for (int kt = 0; kt < nk; ++kt) {
        int cur = kt & 1;
        if (kt + 1 < nk) stage(cur ^ 1, (kt + 1) * 64);
#pragma unroll
        for (int kk = 0; kk < 2; ++kk) {
            short8 af[4], bqf[4];
#pragma unroll
            for (int mi = 0; mi < 4; ++mi) {
                int row = wr * 64 + mi * 16 + lm;
                int cs = kk * 4 + lg;
                af[mi] = *(const short8*)&As[cur][row * 64 + ((cs ^ (row & 7)) * 8)];
            }
#pragma unroll
            for (int ni = 0; ni < 4; ++ni) {
                int row = wc * 64 + ni * 16 + lm;
                int cs = kk * 4 + lg;
                bqf[ni] = *(const short8*)&Bs[cur][row * 64 + ((cs ^ (row & 7)) * 8)];
            }
#pragma unroll
            for (int mi = 0; mi < 4; ++mi)
#pragma unroll
                for (int ni = 0; ni < 4; ++ni)
                    acc[mi][ni] = __builtin_amdgcn_mfma_f32_16x16x32_bf16(af[mi], bqf[ni], acc[mi][ni], 0, 0, 0);
        }
        __syncthreads();
    }

#pragma unroll
    for (int mi = 0; mi < 4; ++mi) {
        int rbase = m0 + wr * 64 + mi * 16 + lg * 4;
#pragma unroll
        for (int ni = 0; ni < 4; ++ni) {
            int n = n0 + wc * 64 + ni * 16 + lm;
            float bv2 = bias[n];
#pragma unroll
            for (int j = 0; j < 4; ++j) {
                int r = rbase + j;
                float v = acc[mi][ni][j] + bv2;
                if (op == 0) {
                    Qb[(size_t)r * CC + n] = f2bf(v);
                } else if (op == 1) {
                    v *= pk[(size_t)(r / NN) * CC + n];
                    Kb[(size_t)r * CC + n] = f2bf(v);
                } else {
                    v *= pv[(size_t)(r / NN) * CC + n];
                    int b2 = r / NN, rl = r - b2 * NN;
                    Vt[((size_t)b2 * CC + n) * VTK + rl] = f2bf(v);
                }
            }
        }
    }
}

// ---------------------------------------------------------------------------
// Fused prod kernel (dual GEMM, dbuf, BK=32):
//   prod[m,n] = (x_loc@Wploc + b_ploc) * (x_ctx@Wpctx + b_pctx)  (fp32 mult)
// LDS: 4 tiles [128][32] x 2 dbuf = 64 KB.  Swizzle: chunk ^= (row>>1)&3
// (4 chunks/row; spreads 16 lanes across 8 bank-groups -> 2-way, free).
// ---------------------------------------------------------------------------
__global__ __launch_bounds__(256) void gemm_prod(
    const unsigned short* __restrict__ Aloc, const unsigned short* __restrict__ Actx,
    const unsigned short* __restrict__ W0, const unsigned short* __restrict__ W1,
    const float* __restrict__ b0, const float* __restrict__ b1,
    unsigned short* __restrict__ C) {
    __shared__ unsigned short A0s[2][128 * 32];
    __shared__ unsigned short A1s[2][128 * 32];
    __shared__ unsigned short B0s[2][128 * 32];
    __shared__ unsigned short B1s[2][128 * 32];
    const int t = threadIdx.x;
    const int l = t & 63;
    const int wv = t >> 6;
    const int wr = wv >> 1, wc = wv & 1;
    const int lg = l >> 4, lm = l & 15;
    const int wgid = xcd_swz(blockIdx.x, gridDim.x);
    const int m0 = (wgid >> 2) * 128, n0 = (wgid & 3) * 128;

    f32x4 a0[4][4], a1[4][4];
#pragma unroll
    for (int mi = 0; mi < 4; ++mi)
#pragma unroll
        for (int ni = 0; ni < 4; ++ni) { a0[mi][ni] = {0.f,0.f,0.f,0.f}; a1[mi][ni] = {0.f,0.f,0.f,0.f}; }

    auto stage = [&](int buf, int k0) {
#pragma unroll
        for (int i = 0; i < 2; ++i) {
            int lin = t + i * 256;
            int row = lin >> 2, seg = lin & 3;
            int goff = k0 + ((seg ^ ((row >> 1) & 3)) * 8);
            async_ld16(Aloc + (size_t)(m0 + row) * XJLD + goff, &A0s[buf][lin * 8]);
            async_ld16(Actx + (size_t)(m0 + row) * XJLD + goff, &A1s[buf][lin * 8]);
            async_ld16(W0 + (size_t)(n0 + row) * CC + goff, &B0s[buf][lin * 8]);
            async_ld16(W1 + (size_t)(n0 + row) * CC + goff, &B1s[buf][lin * 8]);
        }
    };

    const int nk = CC >> 5;   // 16
    stage(0, 0);
    __syncthreads();
    for (int kt = 0; kt < nk; ++kt) {
        int cur = kt & 1;
        if (kt + 1 < nk) stage(cur ^ 1, (kt + 1) * 32);
        short8 af0[4], af1[4], bf0[4], bf1[4];
#pragma unroll
        for (int mi = 0; mi < 4; ++mi) {
            int row = wr * 64 + mi * 16 + lm;
            int off = row * 32 + ((lg ^ ((row >> 1) & 3)) * 8);
            af0[mi] = *(const short8*)&A0s[cur][off];
            af1[mi] = *(const short8*)&A1s[cur][off];
        }
#pragma unroll
        for (int ni = 0; ni < 4; ++ni) {
            int row = wc * 64 + ni * 16 + lm;
            int off = row * 32 + ((lg ^ ((row >> 1) & 3)) * 8);
            bf0[ni] = *(const short8*)&B0s[cur][off];
            bf1[ni] = *(const short8*)&B1s[cur][off];
        }
#pragma unroll
        for (int mi = 0; mi < 4; ++mi)
#pragma unroll
            for (int ni = 0; ni < 4; ++ni) {
                a0[mi][ni] = __builtin_amdgcn_mfma_f32_16x16x32_bf16(af0[mi], bf0[ni], a0[mi][ni], 0, 0, 0);
                a1[mi][ni] = __builtin_amdgcn_mfma_f32_16x16x32_bf16(af1[mi], bf1[ni], a1[mi][ni], 0, 0, 0);
            }
        __syncthreads();
    }

#pragma unroll
    for (int mi = 0; mi < 4; ++mi) {
        int rbase = m0 + wr * 64 + mi * 16 + lg * 4;
#pragma unroll
        for (int ni = 0; ni < 4; ++ni) {
            int n = n0 + wc * 64 + ni * 16 + lm;
            float bv0 = b0[n], bv1 = b1[n];
#pragma unroll
            for (int j = 0; j < 4; ++j) {
                int r = rbase + j;
                float v = (a0[mi][ni][j] + bv0) * (a1[mi][ni][j] + bv1);
                C[(size_t)r * XJLD + n] = f2bf(v);
            }
        }
    }
}

// ---------------------------------------------------------------------------
// Stem GEMM (fp32 A, reg-staged + rownorm fold, single-buffer BK=64; DUAL
// write to both XJ buffers).  Unchanged structure from R7 (verified).
// ---------------------------------------------------------------------------
__global__ __launch_bounds__(256) void gemm_stem(
    const float* __restrict__ Af, int lda,
    const unsigned short* __restrict__ W, int ldw,
    const float* __restrict__ bias,
    unsigned short* __restrict__ C0, unsigned short* __restrict__ C1,
    int K, const float* __restrict__ arsc) {
    __shared__ unsigned short As[128 * 64];
    __shared__ unsigned short Bs[128 * 64];
    const int t = threadIdx.x;
    const int l = t & 63;
    const int wv = t >> 6;
    const int wr = wv >> 1, wc = wv & 1;
    const int lg = l >> 4, lm = l & 15;
    const int wgid = xcd_swz(blockIdx.x, gridDim.x);
    const int m0 = (wgid >> 2) * 128, n0 = (wgid & 3) * 128;

    f32x4 acc[4][4];
#pragma unroll
    for (int mi = 0; mi < 4; ++mi)
#pragma unroll
        for (int ni = 0; ni < 4; ++ni) acc[mi][ni] = {0.f, 0.f, 0.f, 0.f};

    for (int k0 = 0; k0 < K; k0 += 64) {
        {
            int row = t >> 1, half = t & 1;
            const float* s = Af + (size_t)(m0 + row) * lda + k0 + half * 32;
            float sc = arsc[m0 + row];
#pragma unroll
            for (int c = 0; c < 4; ++c) {
                float4 v0 = *(const float4*)(s + c * 8);
                float4 v1 = *(const float4*)(s + c * 8 + 4);
                short8 h;
                h[0] = (short)f2bf(v0.x * sc); h[1] = (short)f2bf(v0.y * sc);
                h[2] = (short)f2bf(v0.z * sc); h[3] = (short)f2bf(v0.w * sc);
                h[4] = (short)f2bf(v1.x * sc); h[5] = (short)f2bf(v1.y * sc);
                h[6] = (short)f2bf(v1.z * sc); h[7] = (short)f2bf(v1.w * sc);
                int cs = half * 4 + c;
                *(short8*)&As[row * 64 + ((cs ^ (row & 7)) * 8)] = h;
            }
        }
#pragma unroll
        for (int i = 0; i < 4; ++i) {
            int lin = t + i * 256;
            int row = lin >> 3, seg = lin & 7;
            async_ld16(W + (size_t)(n0 + row) * ldw + k0 + ((seg ^ (row & 7)) * 8),
                       &Bs[lin * 8]);
        }
        __syncthreads();
#pragma unroll
        for (int kk = 0; kk < 2; ++kk) {
            short8 af[4], bq[4];
#pragma unroll
            for (int mi = 0; mi < 4; ++mi) {
                int row = wr * 64 + mi * 16 + lm;
                int cs = kk * 4 + lg;
                af[mi] = *(const short8*)&As[row * 64 + ((cs ^ (row & 7)) * 8)];
            }
#pragma unroll
            for (int ni = 0; ni < 4; ++ni) {
                int row = wc * 64 + ni * 16 + lm;
                int cs = kk * 4 + lg;
                bq[ni] = *(const short8*)&Bs[row * 64 + ((cs ^ (row & 7)) * 8)];
            }
#pragma unroll
            for (int mi = 0; mi < 4; ++mi)
#pragma unroll
                for (int ni = 0; ni < 4; ++ni)
                    acc[mi][ni] = __builtin_amdgcn_mfma_f32_16x16x32_bf16(af[mi], bq[ni], acc[mi][ni], 0, 0, 0);
        }
        __syncthreads();
    }
#pragma unroll
    for (int mi = 0; mi < 4; ++mi) {
        int rbase = m0 + wr * 64 + mi * 16 + lg * 4;
#pragma unroll
        for (int ni = 0; ni < 4; ++ni) {
            int n = n0 + wc * 64 + ni * 16 + lm;
            float bv = bias[n];
#pragma unroll
            for (int j = 0; j < 4; ++j) {
                int r = rbase + j;
                unsigned short hv = f2bf(acc[mi][ni][j] + bv);
                C0[(size_t)r * XJLD + n] = hv;
                C1[(size_t)r * XJLD + n] = hv;
            }
        }
    }
}

// ---------------------------------------------------------------------------
// small fp32 GEMM for M=128 rows (qcmd/pk/pv/qIn)
// ---------------------------------------------------------------------------
template <int MODE>
__global__ __launch_bounds__(256) void gemm_small(
    const float* __restrict__ A, const float* __restrict__ W,
    const float* __restrict__ bias, float* __restrict__ C) {
    __shared__ float As[32 * 72];
    __shared__ float Bs[32 * 72];
    const int t = threadIdx.x;
    const int m0 = blockIdx.x * 64, n0 = blockIdx.y * 64;
    const int tr = t >> 4, tc = t & 15;
    float acc[4][4];
#pragma unroll
    for (int i = 0; i < 4; ++i)
#pragma unroll
        for (int j = 0; j < 4; ++j) acc[i][j] = 0.f;

    for (int k0 = 0; k0 < CC; k0 += 32) {
        int row = t >> 2, seg = t & 3;
        {
            const float* s = A + (size_t)(m0 + row) * CC + k0 + seg * 8;
            float4 v0 = *(const float4*)s, v1 = *(const float4*)(s + 4);
            As[(seg * 8 + 0) * 72 + row] = v0.x; As[(seg * 8 + 1) * 72 + row] = v0.y;
            As[(seg * 8 + 2) * 72 + row] = v0.z; As[(seg * 8 + 3) * 72 + row] = v0.w;
            As[(seg * 8 + 4) * 72 + row] = v1.x; As[(seg * 8 + 5) * 72 + row] = v1.y;
            As[(seg * 8 + 6) * 72 + row] = v1.z; As[(seg * 8 + 7) * 72 + row] = v1.w;
        }
        {
            const float* s = W + (size_t)(n0 + row) * CC + k0 + seg * 8;
            float4 v0 = *(const float4*)s, v1 = *(const float4*)(s + 4);
            Bs[(seg * 8 + 0) * 72 + row] = v0.x; Bs[(seg * 8 + 1) * 72 + row] = v0.y;
            Bs[(seg * 8 + 2) * 72 + row] = v0.z; Bs[(seg * 8 + 3) * 72 + row] = v0.w;
            Bs[(seg * 8 + 4) * 72 + row] = v1.x; Bs[(seg * 8 + 5) * 72 + row] = v1.y;
            Bs[(seg * 8 + 6) * 72 + row] = v1.z; Bs[(seg * 8 + 7) * 72 + row] = v1.w;
        }
        __syncthreads();
#pragma unroll
        for (int kk = 0; kk < 32; ++kk) {
            float4 a = *(const float4*)&As[kk * 72 + tr * 4];
            float4 b = *(const float4*)&Bs[kk * 72 + tc * 4];
            float av[4] = {a.x, a.y, a.z, a.w}, bv[4] = {b.x, b.y, b.z, b.w};
#pragma unroll
            for (int i = 0; i < 4; ++i)
#pragma unroll
                for (int j = 0; j < 4; ++j) acc[i][j] = fmaf(av[i], bv[j], acc[i][j]);
        }
        __syncthreads();
    }
#pragma unroll
    for (int i = 0; i < 4; ++i) {
#pragma unroll
        for (int j = 0; j < 4; ++j) {
            int n = n0 + tc * 4 + j;
            float v = acc[i][j] + bias[n];
            if (MODE == 4) v = v > 0.f ? v : expm1f(v);
            C[(size_t)(m0 + tr * 4 + i) * CC + n] = v;
        }
    }
}

// ---------------------------------------------------------------------------
// Per-batch command extraction (fp32)
// ---------------------------------------------------------------------------
__global__ __launch_bounds__(256) void cmd_kernel(
    const float* __restrict__ qcmd, const float* __restrict__ lstm,
    const float* __restrict__ wlogit, const float* __restrict__ blogit,
    const int* __restrict__ qlen, float* __restrict__ cmd) {
    const int b = blockIdx.x;
    const int t = threadIdx.x;
    __shared__ float qw[CC];
    __shared__ float att[LL];
    for (int c = t; c < CC; c += 256) qw[c] = qcmd[b * CC + c] * wlogit[c];
    __syncthreads();
    const int wid = t >> 6, lane = t & 63;
    for (int l = wid; l < LL; l += 4) {
        const float* lp = lstm + ((size_t)b * LL + l) * CC;
        float s = 0.f;
        for (int c = lane; c < CC; c += 64) s = fmaf(qw[c], lp[c], s);
#pragma unroll
        for (int off = 32; off > 0; off >>= 1) s += __shfl_down(s, off);
        if (lane == 0) att[l] = s + blogit[0];
    }
    __syncthreads();
    if (t == 0) {
        int Lq = qlen[b];
        float mx = -1e30f;
        for (int l = 0; l < LL; ++l) {
            if (l >= Lq) att[l] = -1e30f;
            mx = fmaxf(mx, att[l]);
        }
        float sum = 0.f;
        for (int l = 0; l < LL; ++l) { float e = expf(att[l] - mx); att[l] = e; sum += e; }
        float inv = 1.f / sum;
        for (int l = 0; l < LL; ++l) att[l] *= inv;
    }
    __syncthreads();
    for (int c = t; c < CC; c += 256) {
        float s = 0.f;
        for (int l = 0; l < LL; ++l) s = fmaf(att[l], lstm[((size_t)b * LL + l) * CC + c], s);
        cmd[b * CC + c] = s;
    }
}

// ---------------------------------------------------------------------------
// MFMA fused attention (unchanged from R7, verified)
// ---------------------------------------------------------------------------
__global__ __launch_bounds__(256) void attn_mfma_kernel(
    const unsigned short* __restrict__ Qm, const unsigned short* __restrict__ Km,
    const unsigned short* __restrict__ Vt, const int* __restrict__ entnum,
    unsigned short* __restrict__ msg) {
    __shared__ char ldsraw[64 * 132 * 4];
    float* S = (float*)ldsraw;
    unsigned short* Qs = (unsigned short*)ldsraw;
    unsigned short* Ks = (unsigned short*)(ldsraw + 8192);
    const int b = blockIdx.x;
    const int qbase = blockIdx.y * QH;
    const int t = threadIdx.x;
    const int wv = t >> 6, l = t & 63, lg = l >> 4, lm = l & 15;
    const unsigned short* Qp = Qm + ((size_t)b * NN + qbase) * CC;
    const unsigned short* Kp = Km + (size_t)b * NN * CC;

    f32x4 sacc[7];
#pragma unroll
    for (int i = 0; i < 7; ++i) sacc[i] = {0.f, 0.f, 0.f, 0.f};

    for (int k0 = 0; k0 < CC; k0 += 64) {
#pragma unroll
        for (int i = 0; i < 2; ++i) {
            int lin = t + i * 256;
            int row = lin >> 3, seg = lin & 7;
            async_ld16(Qp + (size_t)row * CC + k0 + ((seg ^ (row & 7)) * 8), &Qs[lin * 8]);
        }
#pragma unroll
        for (int i = 0; i < 4; ++i) {
            int lin = t + i * 256;
            if (lin < 896) {
                int row = lin >> 3, seg = lin & 7;
                async_ld16(Kp + (size_t)row * CC + k0 + ((seg ^ (row & 7)) * 8), &Ks[lin * 8]);
            }
        }
        __syncthreads();
#pragma unroll
        for (int kk = 0; kk < 2; ++kk) {
            int arow = wv * 16 + lm;
            int cs = kk * 4 + lg;
            short8 a = *(const short8*)&Qs[arow * 64 + ((cs ^ (arow & 7)) * 8)];
#pragma unroll
            for (int nf = 0; nf < 7; ++nf) {
                int brow = nf * 16 + lm;
                short8 bb = *(const short8*)&Ks[brow * 64 + ((cs ^ (brow & 7)) * 8)];
                sacc[nf] = __builtin_amdgcn_mfma_f32_16x16x32_bf16(a, bb, sacc[nf], 0, 0, 0);
            }
        }
        __syncthreads();
    }
#pragma unroll
    for (int nf = 0; nf < 7; ++nf)
#pragma unroll
        for (int j = 0; j < 4; ++j)
            S[(wv * 16 + lg * 4 + j) * 132 + nf * 16 + lm] = sacc[nf][j] * INV_SQRT_C_F;
    __syncthreads();

    const int en = entnum[b];
    for (int q = wv; q < QH; q += 4) {
        float v0 = (l < en) ? S[q * 132 + l] : -1e30f;
        int k1 = l + 64;
        float v1 = (k1 < en) ? S[q * 132 + k1] : -1e30f;
        float mx = fmaxf(v0, v1);
#pragma unroll
        for (int o = 32; o > 0; o >>= 1) mx = fmaxf(mx, __shfl_xor(mx, o));
        float e0 = (l < en) ? expf(v0 - mx) : 0.f;
        float e1 = (k1 < en) ? expf(v1 - mx) : 0.f;
        float ss = e0 + e1;
#pragma unroll
        for (int o = 32; o > 0; o >>= 1) ss += __shfl_xor(ss, o);
        float inv = 1.f / ss;
        S[q * 132 + l] = e0 * inv;
        S[q * 132 + k1] = e1 * inv;
    }
    __syncthreads();

    f32x4 acc[4][8];
#pragma unroll
    for (int mf = 0; mf < 4; ++mf)
#pragma unroll
        for (int nf = 0; nf < 8; ++nf) acc[mf][nf] = {0.f, 0.f, 0.f, 0.f};

    const unsigned short* Vb = Vt + (size_t)b * CC * VTK;
    for (int ks = 0; ks < 4; ++ks) {
        int k0 = ks * 32;
        short8 pa[4];
#pragma unroll
        for (int mf = 0; mf < 4; ++mf) {
            const float* sp = &S[(mf * 16 + lm) * 132 + k0 + lg * 8];
            short8 h;
#pragma unroll
            for (int jj = 0; jj < 8; ++jj) h[jj] = (short)f2bf(sp[jj]);
            pa[mf] = h;
        }
#pragma unroll
        for (int nf = 0; nf < 8; ++nf) {
            short8 bb = *(const short8*)(Vb + ((size_t)(wv * 128 + nf * 16 + lm)) * VTK + k0 + lg * 8);
#pragma unroll
            for (int mf = 0; mf < 4; ++mf)
                acc[mf][nf] = __builtin_amdgcn_mfma_f32_16x16x32_bf16(pa[mf], bb, acc[mf][nf], 0, 0, 0);
        }
    }
#pragma unroll
    for (int mf = 0; mf < 4; ++mf) {
#pragma unroll
        for (int j = 0; j < 4; ++j) {
            int q = mf * 16 + lg * 4 + j;
            if (q < QH) {
                size_t rb = ((size_t)b * NN + qbase + q) * XJLD;
#pragma unroll
                for (int nf = 0; nf < 8; ++nf)
                    msg[rb + wv * 128 + nf * 16 + lm] = f2bf(acc[mf][nf][j]);
            }
        }
    }
}

// ---------------------------------------------------------------------------
extern "C" void kernel_launch(void* const* d_in, const int* in_sizes, int n_in,
                              void* d_out, int out_size, void* d_ws, size_t ws_size,
                              hipStream_t stream) {
    const float* images   = (const float*)d_in[0];
    const float* q_enc    = (const float*)d_in[1];
    const float* lstm     = (const float*)d_in[2];
    const float* W_initKB = (const float*)d_in[3];
    const float* b_initKB = (const float*)d_in[4];
    const float* initMem  = (const float*)d_in[5];
    const float* W_qIn    = (const float*)d_in[6];
    const float* b_qIn    = (const float*)d_in[7];
    const float* W_qIn2   = (const float*)d_in[8];
    const float* b_qIn2   = (const float*)d_in[9];
    const float* W_logit  = (const float*)d_in[10];
    const float* b_logit  = (const float*)d_in[11];
    const float* W_ploc   = (const float*)d_in[12];
    const float* b_ploc   = (const float*)d_in[13];
    const float* W_pctx   = (const float*)d_in[14];
    const float* b_pctx   = (const float*)d_in[15];
    const float* W_q      = (const float*)d_in[16];
    const float* b_q      = (const float*)d_in[17];
    const float* W_k      = (const float*)d_in[18];
    const float* b_k      = (const float*)d_in[19];
    const float* W_v      = (const float*)d_in[20];
    const float* b_v      = (const float*)d_in[21];
    const float* W_pk     = (const float*)d_in[22];
    const float* b_pk     = (const float*)d_in[23];
    const float* W_pv     = (const float*)d_in[24];
    const float* b_pv     = (const float*)d_in[25];
    const float* W_mem    = (const float*)d_in[26];
    const float* b_mem    = (const float*)d_in[27];
    const float* W_comb   = (const float*)d_in[28];
    const float* b_comb   = (const float*)d_in[29];
    const int* q_length   = (const int*)d_in[30];
    const int* entity_num = (const int*)d_in[31];
    (void)in_sizes; (void)n_in; (void)out_size; (void)ws_size;

    // ---- workspace carve ----
    char* p = (char*)d_ws;
    auto alloc = [&](size_t bytes) { char* q = p; p += (bytes + 255) & ~(size_t)255; return q; };
    unsigned short* XJ0 = (unsigned short*)alloc((size_t)ROWS * XJLD * 2);
    unsigned short* XJ1 = (unsigned short*)alloc((size_t)ROWS * XJLD * 2);
    unsigned short* Qb  = (unsigned short*)alloc((size_t)ROWS * CC * 2);
    unsigned short* Kb  = (unsigned short*)alloc((size_t)ROWS * CC * 2);
    unsigned short* Vt  = (unsigned short*)alloc((size_t)BB * CC * VTK * 2);
    unsigned short* Wbf = (unsigned short*)alloc((size_t)5013504 * 2);
    float* qcb  = (float*)alloc((size_t)BB * CC * 4);
    float* qcmd = (float*)alloc((size_t)BB * CC * 4);
    float* cmd  = (float*)alloc((size_t)BB * CC * 4);
    float* pk   = (float*)alloc((size_t)BB * CC * 4);
    float* pv   = (float*)alloc((size_t)BB * CC * 4);
    float* invn = (float*)alloc((size_t)ROWS * 4);

    // bf16 weight offsets (elements)
    unsigned short* Wi_init = Wbf + 0;
    unsigned short* Wi_ploc = Wbf + 1081344;
    unsigned short* Wi_pctx = Wbf + 1343488;
    unsigned short* Wi_q    = Wbf + 1605632;
    unsigned short* Wi_k    = Wbf + 2392064;
    unsigned short* Wi_v    = Wbf + 3178496;
    unsigned short* Wi_mem  = Wbf + 3964928;
    unsigned short* Wi_comb = Wbf + 4489216;

    auto cvt = [&](const float* src, unsigned short* dst, size_t n) {
        int n4 = (int)(n / 4);
        cvt_kernel<<<dim3((n4 + 255) / 256), dim3(256), 0, stream>>>(src, dst, n4);
    };

    // ---- stem ----
    rownorm_kernel<<<dim3(ROWS), dim3(256), 0, stream>>>(images, invn);
    zero16_kernel<<<dim3(((int)((size_t)BB * CC * VTK * 2 / 16) + 255) / 256), dim3(256), 0, stream>>>(
        (uint4*)Vt, (int)((size_t)BB * CC * VTK * 2 / 16));
    cvt(W_initKB, Wi_init, (size_t)CC * DFEAT);
    cvt(W_ploc,  Wi_ploc, (size_t)CC * CC);
    cvt(W_pctx,  Wi_pctx, (size_t)CC * CC);
    cvt(W_q,     Wi_q,    (size_t)CC * 3 * CC);
    cvt(W_k,     Wi_k,    (size_t)CC * 3 * CC);
    cvt(W_v,     Wi_v,    (size_t)CC * 3 * CC);
    cvt(W_mem,   Wi_mem,  (size_t)CC * 2 * CC);
    cvt(W_comb,  Wi_comb, (size_t)CC * 2 * CC);

    dim3 blk(256);
    dim3 g400((ROWS / 128) * 4);
    gemm_stem<<<g400, blk, 0, stream>>>(images, DFEAT, Wi_init, DFEAT, b_initKB,
                                        XJ0, XJ1, DFEAT, invn);
    bcast_kernel<<<dim3((ROWS * CC + 255) / 256), dim3(256), 0, stream>>>(initMem, XJ0);
    gemm_small<4><<<dim3(BB / 64, 8), blk, 0, stream>>>(q_enc, W_qIn, b_qIn, qcb);

    for (int t = 0; t < TT; ++t) {
        unsigned short* R  = (t & 1) ? XJ1 : XJ0;
        unsigned short* Wr = (t & 1) ? XJ0 : XJ1;
        // textual command
        gemm_small<0><<<dim3(BB / 64, 8), blk, 0, stream>>>(
            qcb, W_qIn2 + (size_t)t * CC * CC, b_qIn2 + (size_t)t * CC, qcmd);
        cmd_kernel<<<dim3(BB), blk, 0, stream>>>(qcmd, lstm, W_logit, b_logit, q_length, cmd);
        gemm_small<0><<<dim3(BB / 64, 8), blk, 0, stream>>>(cmd, W_pk, b_pk, pk);
        gemm_small<0><<<dim3(BB / 64, 8), blk, 0, stream>>>(cmd, W_pv, b_pv, pv);
        // prod = (x_loc@Wploc+b) * (xc@Wpctx+b)  -> R col 1024 (fused, fp32 mult)
        gemm_prod<<<g400, blk, 0, stream>>>(R, R + CC, Wi_ploc, Wi_pctx,
                                            b_ploc, b_pctx, R + 2 * CC);
        // fused Q/K/V over x_joint (K=1536)
        gemm_qkv<<<dim3((ROWS / 128) * 12), blk, 0, stream>>>(
            R, Wi_q, Wi_k, Wi_v, b_q, b_k, b_v, Qb, Kb, Vt, pk, pv);
        // attention -> message into R col 1024
        attn_mfma_kernel<<<dim3(BB, 2), blk, 0, stream>>>(Qb, Kb, Vt, entity_num, R + 2 * CC);
        // x_ctx_new = [xc | message] @ W_mem.T + b  -> Wr col 512
        gemm_dbuf<0><<<g400, blk, 0, stream>>>(R + CC, XJLD, Wi_mem, 2 * CC, b_mem,
                                               Wr + CC, XJLD, 2 * CC);
    }
    // output = [x_loc | x_ctx] @ W_comb.T + b
    gemm_dbuf<1><<<g400, blk, 0, stream>>>(XJ0, XJLD, Wi_comb, 2 * CC, b_comb,
                                           (float*)d_out, CC, 2 * CC);
}